// Round 8
// baseline (310.115 us; speedup 1.0000x reference)
//
#include <hip/hip_runtime.h>

#define B_ 4
#define T_ 4096
#define D_ 1024
#define R_ (B_*T_)
#define CHUNK_ 64
#define NCH_ (T_/CHUNK_)
#define EPS_ 1.1920929e-07f

typedef unsigned short ushort_t;
typedef __attribute__((ext_vector_type(8))) short short8;
typedef __attribute__((ext_vector_type(4))) float f32x4;

__device__ __forceinline__ float silu_f(float v){ return v / (1.0f + __expf(-v)); }

__device__ __forceinline__ ushort_t f2bf(float f){
    unsigned u = __float_as_uint(f);
    unsigned r = u + 0x7fffu + ((u>>16)&1u);
    return (ushort_t)(r>>16);
}
__device__ __forceinline__ float bf2f(ushort_t s){ return __uint_as_float(((unsigned)s)<<16); }

__device__ __forceinline__ f32x4 mfma16(short8 a, short8 b, f32x4 c){
    return __builtin_amdgcn_mfma_f32_16x16x32_bf16(a, b, c, 0, 0, 0);
}

// ---------------- prep: weight cvt (bf16) + scalar setup + apow table ----------------
__global__ void prep_k(const float* __restrict__ s0, const float* __restrict__ s1,
                       const float* __restrict__ s2, const float* __restrict__ s3,
                       const float* __restrict__ s4, const float* __restrict__ s5,
                       ushort_t* __restrict__ d0, ushort_t* __restrict__ d1,
                       ushort_t* __restrict__ d2, ushort_t* __restrict__ d3,
                       ushort_t* __restrict__ d4, ushort_t* __restrict__ d5,
                       const float* __restrict__ logA_seq, const float* __restrict__ logdt_seq,
                       const float* __restrict__ logA_dep, const float* __restrict__ logdt_dep,
                       const int* __restrict__ active_k,
                       float* __restrict__ aseq, float* __restrict__ apowC,
                       float* __restrict__ gain, float* __restrict__ apowtab){
    int i = blockIdx.x*256 + threadIdx.x;
    if      (i < 65536)   d0[i] = f2bf(s0[i]);
    else if (i < 131072)  d1[i-65536] = f2bf(s1[i-65536]);
    else if (i < 327680)  d2[i-131072] = f2bf(s2[i-131072]);
    else if (i < 393216)  d3[i-327680] = f2bf(s3[i-327680]);
    else if (i < 458752)  d4[i-393216] = f2bf(s4[i-393216]);
    else if (i < 524288)  d5[i-458752] = f2bf(s5[i-458752]);
    else if (i < 524288 + D_){
        int d = i - 524288;
        float K = (float)(*active_k);
        float a = expf(-expf(logA_seq[d]) * expf(logdt_seq[d]));
        a = fmaxf(a, 1e-6f);
        aseq[d] = a;
        apowC[d] = powf(a, (float)CHUNK_);
        // apowtab[s][d] = a^(s+1), s = row index within 64-chunk
        float ap = a;
        for (int s2=0;s2<CHUNK_;++s2){ apowtab[s2*D_ + d] = ap; ap *= a; }
        float g;
        if (d < 128) {
            g = K;
        } else {
            float ad = expf(-expf(logA_dep[d-128]) * expf(logdt_dep[d-128]));
            float om = 1.0f - ad;
            if (fabsf(om) < 1e-6f) g = K;
            else g = (1.0f - powf(ad, K)) / fmaxf(om, 1e-8f);
        }
        gain[d] = g;
    }
}

// ---------------- rms_norm(x) -> e bf16 ----------------
__global__ __launch_bounds__(256) void rmsbf_k(const float* __restrict__ x, ushort_t* __restrict__ e){
    int row = blockIdx.x;
    int tid = threadIdx.x;
    float4 v = ((const float4*)(x + (size_t)row*D_))[tid];
    float ss = v.x*v.x + v.y*v.y + v.z*v.z + v.w*v.w;
    for (int off=32; off; off>>=1) ss += __shfl_down(ss, off, 64);
    __shared__ float red[4];
    if ((tid&63)==0) red[tid>>6] = ss;
    __syncthreads();
    float tot = red[0]+red[1]+red[2]+red[3];
    float scale = 1.0f / sqrtf(tot*(1.0f/D_) + EPS_);
    ushort4 o;
    o.x = f2bf(v.x*scale); o.y = f2bf(v.y*scale); o.z = f2bf(v.z*scale); o.w = f2bf(v.w*scale);
    ((ushort4*)(e + (size_t)row*D_))[tid] = o;
}

// ---------------- bd2s: blockdiags + fused local chunk scan ----------------
__global__ __launch_bounds__(256) void bd2s_k(const ushort_t* __restrict__ e,
        const ushort_t* __restrict__ wseq, const ushort_t* __restrict__ wdep,
        const float* __restrict__ gain, const float* __restrict__ aseq,
        ushort_t* __restrict__ hsum, float* __restrict__ carry){
    __shared__ __align__(16) ushort_t sd[4][16][72];
    __shared__ __align__(16) ushort_t sh[4][16][72];
    int wave = threadIdx.x>>6, lane = threadIdx.x&63;
    int m = lane&15, quad = lane>>4;
    int orow = lane>>2, oq = lane&3;
    int n = blockIdx.y;
    int chunk0 = blockIdx.x*256 + wave*64;

    short8 bs[2][4], bd[2][4];
    #pragma unroll
    for (int s=0;s<2;++s)
        #pragma unroll
        for (int c=0;c<4;++c){
            bs[s][c] = *(const short8*)(wseq + n*4096 + (c*16+m)*64 + s*32 + quad*8);
            bd[s][c] = *(const short8*)(wdep + n*4096 + (c*16+m)*64 + s*32 + quad*8);
        }
    float g[4];
    #pragma unroll
    for (int c=0;c<4;++c) g[c] = gain[n*64 + c*16 + m];

    float a = aseq[n*64 + lane];
    float hh = 0.f;

    #pragma unroll
    for (int t=0;t<4;++t){
        int r0 = chunk0 + t*16;
        const ushort_t* ab = e + (size_t)(r0+m)*D_ + n*64 + quad*8;
        short8 a0 = *(const short8*)ab;
        short8 a1 = *(const short8*)(ab + 32);
        f32x4 accs[4], accd[4];
        #pragma unroll
        for (int c=0;c<4;++c){
            accs[c]=(f32x4)0.f; accd[c]=(f32x4)0.f;
            accs[c]=mfma16(a0, bs[0][c], accs[c]);
            accd[c]=mfma16(a0, bd[0][c], accd[c]);
            accs[c]=mfma16(a1, bs[1][c], accs[c]);
            accd[c]=mfma16(a1, bd[1][c], accd[c]);
        }
        #pragma unroll
        for (int c=0;c<4;++c)
            #pragma unroll
            for (int r=0;r<4;++r){
                sd[wave][quad*4+r][c*16+m] = f2bf(silu_f(accs[c][r]));
                sh[wave][quad*4+r][c*16+m] = f2bf(g[c]*silu_f(accd[c][r]));
            }
        #pragma unroll
        for (int s=0;s<16;++s){
            hh = fmaf(a, hh, bf2f(sd[wave][s][lane]));
            sd[wave][s][lane] = f2bf(hh + bf2f(sh[wave][s][lane]));
        }
        ushort_t* db = hsum + (size_t)(r0+orow)*D_ + n*64;
        #pragma unroll
        for (int it=0;it<2;++it)
            *(short8*)(db + (it*4+oq)*8) = *(const short8*)&sd[wave][orow][(it*4+oq)*8];
    }
    carry[(size_t)(chunk0>>6)*D_ + n*64 + lane] = hh;
}

// ---------------- scan2: serial prefix over chunk carries ----------------
__global__ __launch_bounds__(256) void scan2_k(float* __restrict__ carry, const float* __restrict__ apowC){
    int tid = blockIdx.x*256 + threadIdx.x;      // B_*D_ threads
    int d = tid & (D_-1);
    int b = tid >> 10;
    float aC = apowC[d];
    float pref = 0.f;
    for (int c=0;c<NCH_;++c){
        size_t idx = (size_t)(b*NCH_+c)*D_ + d;
        float s = carry[idx];
        carry[idx] = pref;
        pref = fmaf(aC, pref, s);
    }
}

// ---------------- scan3s: hn = rmsnorm(hsum + P*a^(s+1)) in ONE pass ----------------
__global__ __launch_bounds__(256) void scan3s_k(const ushort_t* __restrict__ hsum,
                                                const float* __restrict__ aseq,
                                                const float* __restrict__ carry,
                                                const float* __restrict__ apowtab,
                                                ushort_t* __restrict__ hn){
    __shared__ float part[4][4];
    __shared__ float scl[8];
    int tid = threadIdx.x;
    int lane = tid & 63, wave = tid >> 6;
    int cg = tid & 127;        // col group (8 cols)
    int rp = tid >> 7;         // row parity (0/1)
    int d0 = cg*8;
    int row0 = blockIdx.x*8;   // 8 rows, all within one 64-chunk
    int bc = row0 >> 6;
    int s0 = row0 & 63;

    float a2[8], P[8], apow[8];
    #pragma unroll
    for (int j=0;j<8;++j){
        float aj = aseq[d0+j];
        a2[j] = aj*aj;
        P[j]  = carry[(size_t)bc*D_ + d0 + j];
        apow[j] = apowtab[(size_t)(s0 + rp)*D_ + d0 + j];   // a^(s+1) at first row
    }

    float hf[4][8];
    #pragma unroll
    for (int i=0;i<4;++i){
        int row = row0 + i*2 + rp;
        short8 v = *(const short8*)(hsum + (size_t)row*D_ + d0);
        float ss = 0.f;
        #pragma unroll
        for (int j=0;j<8;++j){
            float f = bf2f((ushort_t)v[j]) + P[j]*apow[j];
            hf[i][j] = f;
            ss += f*f;
            apow[j] *= a2[j];
        }
        for (int off=32; off; off>>=1) ss += __shfl_down(ss, off, 64);
        if (lane==0) part[wave][i] = ss;
    }
    __syncthreads();
    if (tid < 8){
        int r = tid;                 // row index within block
        int rr = r & 1, ii = r >> 1;
        float sum = part[rr*2][ii] + part[rr*2+1][ii];
        scl[r] = rsqrtf(sum*(1.0f/D_) + EPS_);
    }
    __syncthreads();
    #pragma unroll
    for (int i=0;i<4;++i){
        int rloc = i*2 + rp;
        float sc = scl[rloc];
        short8 o;
        #pragma unroll
        for (int j=0;j<8;++j) o[j] = (short)f2bf(hf[i][j]*sc);
        *(short8*)(hn + (size_t)(row0 + rloc)*D_ + d0) = o;
    }
}

// ---------------- post: r = silu(concat[hn,e,eshift] @ wpost^T) bf16 ----------------
// ILP experiment: ALL 12 activation fragments issued upfront (af[2][6], ~12KB/wave
// in flight vs ~2KB when loaded inside the s-loop), weights consumed per-s after.
__global__ __launch_bounds__(256) void post_k(const ushort_t* __restrict__ hn,
                                              const ushort_t* __restrict__ e,
                                              const ushort_t* __restrict__ wpost, ushort_t* __restrict__ rout){
    __shared__ __align__(16) ushort_t st[4][16][72];
    int wave = threadIdx.x>>6, lane = threadIdx.x&63;
    int m = lane&15, quad = lane>>4;
    int orow = lane>>2, oq = lane&3;
    int n = blockIdx.y;
    int row0 = blockIdx.x*128 + wave*32 + m;

    short8 af[2][6];
    #pragma unroll
    for (int t=0;t<2;++t){
        int row = row0 + t*16;
        #pragma unroll
        for (int s=0;s<6;++s){
            int g0 = n*192 + s*32;
            if (g0 < 1024){
                af[t][s] = *(const short8*)(hn + (size_t)row*D_ + g0 + quad*8);
            } else if (g0 < 2048){
                af[t][s] = *(const short8*)(e + (size_t)row*D_ + (g0-1024) + quad*8);
            } else {
                if ((row & (T_-1)) == 0) af[t][s] = short8{0,0,0,0,0,0,0,0};
                else af[t][s] = *(const short8*)(e + (size_t)(row-1)*D_ + (g0-2048) + quad*8);
            }
        }
    }

    f32x4 acc[2][4];
    #pragma unroll
    for (int t=0;t<2;++t)
        #pragma unroll
        for (int c=0;c<4;++c) acc[t][c]=(f32x4)0.f;

    #pragma unroll 2
    for (int s=0;s<6;++s){
        short8 bw[4];
        #pragma unroll
        for (int c=0;c<4;++c)
            bw[c] = *(const short8*)(wpost + n*(64*192) + (c*16+m)*192 + s*32 + quad*8);
        #pragma unroll
        for (int t=0;t<2;++t)
            #pragma unroll
            for (int c=0;c<4;++c)
                acc[t][c] = mfma16(af[t][s], bw[c], acc[t][c]);
    }
    #pragma unroll
    for (int t=0;t<2;++t){
        int r0 = blockIdx.x*128 + wave*32 + t*16;
        #pragma unroll
        for (int c=0;c<4;++c)
            #pragma unroll
            for (int r=0;r<4;++r)
                st[wave][quad*4+r][c*16+m] = f2bf(silu_f(acc[t][c][r]));
        ushort_t* db = rout + (size_t)(r0+orow)*D_ + n*64;
        #pragma unroll
        for (int it=0;it<2;++it)
            *(short8*)(db + (it*4+oq)*8) = *(const short8*)&st[wave][orow][(it*4+oq)*8];
    }
}

// ---------------- rlow = r @ lrB^T (K=1024 -> 64) bf16, split-K over 4 waves ----------------
// ILP: all 8 r-fragments (the only HBM reads) issued upfront.
__global__ __launch_bounds__(256) void rlow_k(const ushort_t* __restrict__ r, const ushort_t* __restrict__ lrB,
                                              ushort_t* __restrict__ rlow){
    __shared__ __align__(16) float sacc[4][16][68];
    int wave = threadIdx.x>>6, lane = threadIdx.x&63;
    int m = lane&15, quad = lane>>4;
    int r0 = blockIdx.x*16;
    const ushort_t* ab = r + (size_t)(r0+m)*D_ + wave*256 + quad*8;
    short8 a[8];
    #pragma unroll
    for (int s=0;s<8;++s) a[s] = *(const short8*)(ab + s*32);
    f32x4 acc[4];
    #pragma unroll
    for (int c=0;c<4;++c) acc[c]=(f32x4)0.f;
    #pragma unroll
    for (int s=0;s<8;++s){
        #pragma unroll
        for (int c=0;c<4;++c){
            short8 b = *(const short8*)(lrB + (c*16+m)*1024 + wave*256 + s*32 + quad*8);
            acc[c] = mfma16(a[s], b, acc[c]);
        }
    }
    #pragma unroll
    for (int c=0;c<4;++c)
        #pragma unroll
        for (int r2=0;r2<4;++r2)
            sacc[wave][quad*4+r2][c*16+m] = acc[c][r2];
    __syncthreads();
    int row  = threadIdx.x>>4;        // 0..15
    int col4 = (threadIdx.x&15)*4;    // 0..60 step 4
    float4 v0 = *(const float4*)&sacc[0][row][col4];
    float4 v1 = *(const float4*)&sacc[1][row][col4];
    float4 v2 = *(const float4*)&sacc[2][row][col4];
    float4 v3 = *(const float4*)&sacc[3][row][col4];
    ushort4 o;
    o.x = f2bf(v0.x+v1.x+v2.x+v3.x);
    o.y = f2bf(v0.y+v1.y+v2.y+v3.y);
    o.z = f2bf(v0.z+v1.z+v2.z+v3.z);
    o.w = f2bf(v0.w+v1.w+v2.w+v3.w);
    *(ushort4*)(rlow + (size_t)(r0+row)*64 + col4) = o;
}

// ---------------- out = x + r@wloc^T + rlow@lrA^T ----------------
__global__ __launch_bounds__(256) void out_k(const float* __restrict__ x, const ushort_t* __restrict__ r,
        const ushort_t* __restrict__ rlow, const ushort_t* __restrict__ wloc, const ushort_t* __restrict__ lrA,
        float* __restrict__ out){
    __shared__ __align__(16) float st[4][16][68];
    int wave = threadIdx.x>>6, lane = threadIdx.x&63;
    int m = lane&15, quad = lane>>4;
    int orow = lane>>2, oq = lane&3;
    int n = blockIdx.y;

    short8 wl[2][4], la[4][2];
    #pragma unroll
    for (int c=0;c<4;++c)
        #pragma unroll
        for (int s=0;s<2;++s){
            wl[s][c] = *(const short8*)(wloc + n*4096 + (c*16+m)*64 + s*32 + quad*8);
            la[c][s] = *(const short8*)(lrA + (size_t)(n*64 + c*16 + m)*64 + s*32 + quad*8);
        }
    #pragma unroll
    for (int t=0;t<2;++t){
        int r0 = blockIdx.x*128 + wave*32 + t*16;
        const float* xb = x + (size_t)(r0+orow)*D_ + n*64;
        float4 xv[4];
        #pragma unroll
        for (int it=0;it<4;++it) xv[it] = *(const float4*)(xb + (it*4+oq)*4);

        const ushort_t* lb = rlow + (size_t)(r0+m)*64 + quad*8;
        short8 al0 = *(const short8*)lb;
        short8 al1 = *(const short8*)(lb + 32);
        const ushort_t* ab = r + (size_t)(r0+m)*D_ + n*64 + quad*8;
        short8 ar0 = *(const short8*)ab;
        short8 ar1 = *(const short8*)(ab + 32);
        f32x4 acc[4];
        #pragma unroll
        for (int c=0;c<4;++c){
            acc[c]=(f32x4)0.f;
            acc[c]=mfma16(al0, la[c][0], acc[c]);
            acc[c]=mfma16(al1, la[c][1], acc[c]);
            acc[c]=mfma16(ar0, wl[0][c], acc[c]);
            acc[c]=mfma16(ar1, wl[1][c], acc[c]);
        }
        #pragma unroll
        for (int c=0;c<4;++c)
            #pragma unroll
            for (int r2=0;r2<4;++r2)
                st[wave][quad*4+r2][c*16+m] = acc[c][r2];
        float* ob = out + (size_t)(r0+orow)*D_ + n*64;
        #pragma unroll
        for (int it=0;it<4;++it){
            float4 v = *(const float4*)&st[wave][orow][(it*4+oq)*4];
            v.x += xv[it].x; v.y += xv[it].y; v.z += xv[it].z; v.w += xv[it].w;
            *(float4*)(ob + (it*4+oq)*4) = v;
        }
    }
}

extern "C" void kernel_launch(void* const* d_in, const int* in_sizes, int n_in,
                              void* d_out, int out_size, void* d_ws, size_t ws_size,
                              hipStream_t stream) {
    const float* x         = (const float*)d_in[0];
    const int*   active_k  = (const int*)  d_in[1];
    const float* b_seq_w   = (const float*)d_in[2];
    const float* b_depth_w = (const float*)d_in[3];
    const float* w_post_w  = (const float*)d_in[4];
    const float* w_local_w = (const float*)d_in[5];
    const float* lr_A      = (const float*)d_in[6];
    const float* lr_B      = (const float*)d_in[7];
    const float* logA_seq  = (const float*)d_in[8];
    const float* logdt_seq = (const float*)d_in[9];
    const float* logA_dep  = (const float*)d_in[10];
    const float* logdt_dep = (const float*)d_in[11];

    float* ws      = (float*)d_ws;
    float* carry   = ws;                             // B_*NCH_*D_ = 262144
    float* aseq    = carry + (size_t)B_*NCH_*D_;
    float* apowC   = aseq + D_;
    float* gain    = apowC + D_;
    float* apowtab = gain + D_;                      // CHUNK_*D_ = 65536
    ushort_t* ub       = (ushort_t*)(apowtab + (size_t)CHUNK_*D_);
    ushort_t* e_bf     = ub;                         // R_*D_
    ushort_t* hsum_bf  = e_bf + (size_t)R_*D_;       // R_*D_ (scanned drive + hdep)
    ushort_t* hn_bf    = hsum_bf + (size_t)R_*D_;    // R_*D_ (normalized h)
    ushort_t* r_bf     = hn_bf + (size_t)R_*D_;      // R_*D_
    ushort_t* rlow_bf  = r_bf + (size_t)R_*D_;       // R_*64
    ushort_t* wseq_bf  = rlow_bf + (size_t)R_*64;    // 65536
    ushort_t* wdep_bf  = wseq_bf + 65536;
    ushort_t* wpost_bf = wdep_bf + 65536;            // 196608
    ushort_t* wloc_bf  = wpost_bf + 196608;
    ushort_t* lrA_bf   = wloc_bf + 65536;
    ushort_t* lrB_bf   = lrA_bf + 65536;

    prep_k<<<(524288 + D_ + 255)/256, 256, 0, stream>>>(
        b_seq_w, b_depth_w, w_post_w, w_local_w, lr_A, lr_B,
        wseq_bf, wdep_bf, wpost_bf, wloc_bf, lrA_bf, lrB_bf,
        logA_seq, logdt_seq, logA_dep, logdt_dep, active_k, aseq, apowC, gain, apowtab);

    rmsbf_k <<<R_, 256, 0, stream>>>(x, e_bf);
    bd2s_k  <<<dim3(R_/256, 16), 256, 0, stream>>>(e_bf, wseq_bf, wdep_bf, gain, aseq,
                                                   hsum_bf, carry);
    scan2_k <<<(B_*D_)/256, 256, 0, stream>>>(carry, apowC);
    scan3s_k<<<R_/8, 256, 0, stream>>>(hsum_bf, aseq, carry, apowtab, hn_bf);
    post_k  <<<dim3(R_/128, 16), 256, 0, stream>>>(hn_bf, e_bf, wpost_bf, r_bf);
    rlow_k  <<<R_/16, 256, 0, stream>>>(r_bf, lrB_bf, rlow_bf);
    out_k   <<<dim3(R_/128, 16), 256, 0, stream>>>(x, r_bf, rlow_bf, wloc_bf, lrA_bf, (float*)d_out);
}

// Round 9
// 308.387 us; speedup vs baseline: 1.0056x; 1.0056x over previous
//
#include <hip/hip_runtime.h>

#define B_ 4
#define T_ 4096
#define D_ 1024
#define R_ (B_*T_)
#define CHUNK_ 64
#define NCH_ (T_/CHUNK_)
#define EPS_ 1.1920929e-07f

typedef unsigned short ushort_t;
typedef __attribute__((ext_vector_type(8))) short short8;
typedef __attribute__((ext_vector_type(4))) float f32x4;

__device__ __forceinline__ float silu_f(float v){ return v / (1.0f + __expf(-v)); }

__device__ __forceinline__ ushort_t f2bf(float f){
    unsigned u = __float_as_uint(f);
    unsigned r = u + 0x7fffu + ((u>>16)&1u);
    return (ushort_t)(r>>16);
}
__device__ __forceinline__ float bf2f(ushort_t s){ return __uint_as_float(((unsigned)s)<<16); }

__device__ __forceinline__ f32x4 mfma16(short8 a, short8 b, f32x4 c){
    return __builtin_amdgcn_mfma_f32_16x16x32_bf16(a, b, c, 0, 0, 0);
}

// ---------------- prep: weight cvt (bf16) + scalar setup + apow table ----------------
__global__ void prep_k(const float* __restrict__ s0, const float* __restrict__ s1,
                       const float* __restrict__ s2, const float* __restrict__ s3,
                       const float* __restrict__ s4, const float* __restrict__ s5,
                       ushort_t* __restrict__ d0, ushort_t* __restrict__ d1,
                       ushort_t* __restrict__ d2, ushort_t* __restrict__ d3,
                       ushort_t* __restrict__ d4, ushort_t* __restrict__ d5,
                       const float* __restrict__ logA_seq, const float* __restrict__ logdt_seq,
                       const float* __restrict__ logA_dep, const float* __restrict__ logdt_dep,
                       const int* __restrict__ active_k,
                       float* __restrict__ aseq, float* __restrict__ apowC,
                       float* __restrict__ gain, float* __restrict__ apowtab){
    int i = blockIdx.x*256 + threadIdx.x;
    if      (i < 65536)   d0[i] = f2bf(s0[i]);
    else if (i < 131072)  d1[i-65536] = f2bf(s1[i-65536]);
    else if (i < 327680)  d2[i-131072] = f2bf(s2[i-131072]);
    else if (i < 393216)  d3[i-327680] = f2bf(s3[i-327680]);
    else if (i < 458752)  d4[i-393216] = f2bf(s4[i-393216]);
    else if (i < 524288)  d5[i-458752] = f2bf(s5[i-458752]);
    else if (i < 524288 + D_){
        int d = i - 524288;
        float K = (float)(*active_k);
        float a = expf(-expf(logA_seq[d]) * expf(logdt_seq[d]));
        a = fmaxf(a, 1e-6f);
        aseq[d] = a;
        apowC[d] = powf(a, (float)CHUNK_);
        // apowtab[s][d] = a^(s+1), s = row index within 64-chunk
        float ap = a;
        for (int s2=0;s2<CHUNK_;++s2){ apowtab[s2*D_ + d] = ap; ap *= a; }
        float g;
        if (d < 128) {
            g = K;
        } else {
            float ad = expf(-expf(logA_dep[d-128]) * expf(logdt_dep[d-128]));
            float om = 1.0f - ad;
            if (fabsf(om) < 1e-6f) g = K;
            else g = (1.0f - powf(ad, K)) / fmaxf(om, 1e-8f);
        }
        gain[d] = g;
    }
}

// ---------------- rms_norm(x) -> e bf16 ----------------
__global__ __launch_bounds__(256) void rmsbf_k(const float* __restrict__ x, ushort_t* __restrict__ e){
    int row = blockIdx.x;
    int tid = threadIdx.x;
    float4 v = ((const float4*)(x + (size_t)row*D_))[tid];
    float ss = v.x*v.x + v.y*v.y + v.z*v.z + v.w*v.w;
    for (int off=32; off; off>>=1) ss += __shfl_down(ss, off, 64);
    __shared__ float red[4];
    if ((tid&63)==0) red[tid>>6] = ss;
    __syncthreads();
    float tot = red[0]+red[1]+red[2]+red[3];
    float scale = 1.0f / sqrtf(tot*(1.0f/D_) + EPS_);
    ushort4 o;
    o.x = f2bf(v.x*scale); o.y = f2bf(v.y*scale); o.z = f2bf(v.z*scale); o.w = f2bf(v.w*scale);
    ((ushort4*)(e + (size_t)row*D_))[tid] = o;
}

// ---------------- bd2s: blockdiags + fused local chunk scan ----------------
__global__ __launch_bounds__(256) void bd2s_k(const ushort_t* __restrict__ e,
        const ushort_t* __restrict__ wseq, const ushort_t* __restrict__ wdep,
        const float* __restrict__ gain, const float* __restrict__ aseq,
        ushort_t* __restrict__ hsum, float* __restrict__ carry){
    __shared__ __align__(16) ushort_t sd[4][16][72];
    __shared__ __align__(16) ushort_t sh[4][16][72];
    int wave = threadIdx.x>>6, lane = threadIdx.x&63;
    int m = lane&15, quad = lane>>4;
    int orow = lane>>2, oq = lane&3;
    int n = blockIdx.y;
    int chunk0 = blockIdx.x*256 + wave*64;

    short8 bs[2][4], bd[2][4];
    #pragma unroll
    for (int s=0;s<2;++s)
        #pragma unroll
        for (int c=0;c<4;++c){
            bs[s][c] = *(const short8*)(wseq + n*4096 + (c*16+m)*64 + s*32 + quad*8);
            bd[s][c] = *(const short8*)(wdep + n*4096 + (c*16+m)*64 + s*32 + quad*8);
        }
    float g[4];
    #pragma unroll
    for (int c=0;c<4;++c) g[c] = gain[n*64 + c*16 + m];

    float a = aseq[n*64 + lane];
    float hh = 0.f;

    #pragma unroll
    for (int t=0;t<4;++t){
        int r0 = chunk0 + t*16;
        const ushort_t* ab = e + (size_t)(r0+m)*D_ + n*64 + quad*8;
        short8 a0 = *(const short8*)ab;
        short8 a1 = *(const short8*)(ab + 32);
        f32x4 accs[4], accd[4];
        #pragma unroll
        for (int c=0;c<4;++c){
            accs[c]=(f32x4)0.f; accd[c]=(f32x4)0.f;
            accs[c]=mfma16(a0, bs[0][c], accs[c]);
            accd[c]=mfma16(a0, bd[0][c], accd[c]);
            accs[c]=mfma16(a1, bs[1][c], accs[c]);
            accd[c]=mfma16(a1, bd[1][c], accd[c]);
        }
        #pragma unroll
        for (int c=0;c<4;++c)
            #pragma unroll
            for (int r=0;r<4;++r){
                sd[wave][quad*4+r][c*16+m] = f2bf(silu_f(accs[c][r]));
                sh[wave][quad*4+r][c*16+m] = f2bf(g[c]*silu_f(accd[c][r]));
            }
        #pragma unroll
        for (int s=0;s<16;++s){
            hh = fmaf(a, hh, bf2f(sd[wave][s][lane]));
            sd[wave][s][lane] = f2bf(hh + bf2f(sh[wave][s][lane]));
        }
        ushort_t* db = hsum + (size_t)(r0+orow)*D_ + n*64;
        #pragma unroll
        for (int it=0;it<2;++it)
            *(short8*)(db + (it*4+oq)*8) = *(const short8*)&sd[wave][orow][(it*4+oq)*8];
    }
    carry[(size_t)(chunk0>>6)*D_ + n*64 + lane] = hh;
}

// ---------------- scan2: serial prefix over chunk carries ----------------
__global__ __launch_bounds__(256) void scan2_k(float* __restrict__ carry, const float* __restrict__ apowC){
    int tid = blockIdx.x*256 + threadIdx.x;      // B_*D_ threads
    int d = tid & (D_-1);
    int b = tid >> 10;
    float aC = apowC[d];
    float pref = 0.f;
    for (int c=0;c<NCH_;++c){
        size_t idx = (size_t)(b*NCH_+c)*D_ + d;
        float s = carry[idx];
        carry[idx] = pref;
        pref = fmaf(aC, pref, s);
    }
}

// ---------------- scan3s: hn = rmsnorm(hsum + P*a^(s+1)) in ONE pass ----------------
__global__ __launch_bounds__(256) void scan3s_k(const ushort_t* __restrict__ hsum,
                                                const float* __restrict__ aseq,
                                                const float* __restrict__ carry,
                                                const float* __restrict__ apowtab,
                                                ushort_t* __restrict__ hn){
    __shared__ float part[4][4];
    __shared__ float scl[8];
    int tid = threadIdx.x;
    int lane = tid & 63, wave = tid >> 6;
    int cg = tid & 127;        // col group (8 cols)
    int rp = tid >> 7;         // row parity (0/1)
    int d0 = cg*8;
    int row0 = blockIdx.x*8;   // 8 rows, all within one 64-chunk
    int bc = row0 >> 6;
    int s0 = row0 & 63;

    float a2[8], P[8], apow[8];
    #pragma unroll
    for (int j=0;j<8;++j){
        float aj = aseq[d0+j];
        a2[j] = aj*aj;
        P[j]  = carry[(size_t)bc*D_ + d0 + j];
        apow[j] = apowtab[(size_t)(s0 + rp)*D_ + d0 + j];   // a^(s+1) at first row
    }

    float hf[4][8];
    #pragma unroll
    for (int i=0;i<4;++i){
        int row = row0 + i*2 + rp;
        short8 v = *(const short8*)(hsum + (size_t)row*D_ + d0);
        float ss = 0.f;
        #pragma unroll
        for (int j=0;j<8;++j){
            float f = bf2f((ushort_t)v[j]) + P[j]*apow[j];
            hf[i][j] = f;
            ss += f*f;
            apow[j] *= a2[j];
        }
        for (int off=32; off; off>>=1) ss += __shfl_down(ss, off, 64);
        if (lane==0) part[wave][i] = ss;
    }
    __syncthreads();
    if (tid < 8){
        int r = tid;                 // row index within block
        int rr = r & 1, ii = r >> 1;
        float sum = part[rr*2][ii] + part[rr*2+1][ii];
        scl[r] = rsqrtf(sum*(1.0f/D_) + EPS_);
    }
    __syncthreads();
    #pragma unroll
    for (int i=0;i<4;++i){
        int rloc = i*2 + rp;
        float sc = scl[rloc];
        short8 o;
        #pragma unroll
        for (int j=0;j<8;++j) o[j] = (short)f2bf(hf[i][j]*sc);
        *(short8*)(hn + (size_t)(row0 + rloc)*D_ + d0) = o;
    }
}

// ---------------- post: r = silu(concat[hn,e,eshift] @ wpost^T) bf16 ----------------
// ILP retry: af[2][6] preloaded upfront; __launch_bounds__(256,4) gives the
// register allocator a 128-VGPR budget so af stays in registers (R8's default
// budget chose 52 VGPR + scratch spill: WRITE_SIZE 32->131 MB).
__global__ __launch_bounds__(256, 4) void post_k(const ushort_t* __restrict__ hn,
                                              const ushort_t* __restrict__ e,
                                              const ushort_t* __restrict__ wpost, ushort_t* __restrict__ rout){
    __shared__ __align__(16) ushort_t st[4][16][72];
    int wave = threadIdx.x>>6, lane = threadIdx.x&63;
    int m = lane&15, quad = lane>>4;
    int orow = lane>>2, oq = lane&3;
    int n = blockIdx.y;
    int row0 = blockIdx.x*128 + wave*32 + m;

    short8 af[2][6];
    #pragma unroll
    for (int t=0;t<2;++t){
        int row = row0 + t*16;
        #pragma unroll
        for (int s=0;s<6;++s){
            int g0 = n*192 + s*32;
            if (g0 < 1024){
                af[t][s] = *(const short8*)(hn + (size_t)row*D_ + g0 + quad*8);
            } else if (g0 < 2048){
                af[t][s] = *(const short8*)(e + (size_t)row*D_ + (g0-1024) + quad*8);
            } else {
                if ((row & (T_-1)) == 0) af[t][s] = short8{0,0,0,0,0,0,0,0};
                else af[t][s] = *(const short8*)(e + (size_t)(row-1)*D_ + (g0-2048) + quad*8);
            }
        }
    }

    f32x4 acc[2][4];
    #pragma unroll
    for (int t=0;t<2;++t)
        #pragma unroll
        for (int c=0;c<4;++c) acc[t][c]=(f32x4)0.f;

    #pragma unroll 2
    for (int s=0;s<6;++s){
        short8 bw[4];
        #pragma unroll
        for (int c=0;c<4;++c)
            bw[c] = *(const short8*)(wpost + n*(64*192) + (c*16+m)*192 + s*32 + quad*8);
        #pragma unroll
        for (int t=0;t<2;++t)
            #pragma unroll
            for (int c=0;c<4;++c)
                acc[t][c] = mfma16(af[t][s], bw[c], acc[t][c]);
    }
    #pragma unroll
    for (int t=0;t<2;++t){
        int r0 = blockIdx.x*128 + wave*32 + t*16;
        #pragma unroll
        for (int c=0;c<4;++c)
            #pragma unroll
            for (int r=0;r<4;++r)
                st[wave][quad*4+r][c*16+m] = f2bf(silu_f(acc[t][c][r]));
        ushort_t* db = rout + (size_t)(r0+orow)*D_ + n*64;
        #pragma unroll
        for (int it=0;it<2;++it)
            *(short8*)(db + (it*4+oq)*8) = *(const short8*)&st[wave][orow][(it*4+oq)*8];
    }
}

// ---------------- rlow = r @ lrB^T (K=1024 -> 64) bf16, split-K over 4 waves ----------------
__global__ __launch_bounds__(256) void rlow_k(const ushort_t* __restrict__ r, const ushort_t* __restrict__ lrB,
                                              ushort_t* __restrict__ rlow){
    __shared__ __align__(16) float sacc[4][16][68];
    int wave = threadIdx.x>>6, lane = threadIdx.x&63;
    int m = lane&15, quad = lane>>4;
    int r0 = blockIdx.x*16;
    const ushort_t* ab = r + (size_t)(r0+m)*D_ + wave*256 + quad*8;
    short8 a[8];
    #pragma unroll
    for (int s=0;s<8;++s) a[s] = *(const short8*)(ab + s*32);
    f32x4 acc[4];
    #pragma unroll
    for (int c=0;c<4;++c) acc[c]=(f32x4)0.f;
    #pragma unroll
    for (int s=0;s<8;++s){
        #pragma unroll
        for (int c=0;c<4;++c){
            short8 b = *(const short8*)(lrB + (c*16+m)*1024 + wave*256 + s*32 + quad*8);
            acc[c] = mfma16(a[s], b, acc[c]);
        }
    }
    #pragma unroll
    for (int c=0;c<4;++c)
        #pragma unroll
        for (int r2=0;r2<4;++r2)
            sacc[wave][quad*4+r2][c*16+m] = acc[c][r2];
    __syncthreads();
    int row  = threadIdx.x>>4;        // 0..15
    int col4 = (threadIdx.x&15)*4;    // 0..60 step 4
    float4 v0 = *(const float4*)&sacc[0][row][col4];
    float4 v1 = *(const float4*)&sacc[1][row][col4];
    float4 v2 = *(const float4*)&sacc[2][row][col4];
    float4 v3 = *(const float4*)&sacc[3][row][col4];
    ushort4 o;
    o.x = f2bf(v0.x+v1.x+v2.x+v3.x);
    o.y = f2bf(v0.y+v1.y+v2.y+v3.y);
    o.z = f2bf(v0.z+v1.z+v2.z+v3.z);
    o.w = f2bf(v0.w+v1.w+v2.w+v3.w);
    *(ushort4*)(rlow + (size_t)(r0+row)*64 + col4) = o;
}

// ---------------- out = x + r@wloc^T + rlow@lrA^T ----------------
__global__ __launch_bounds__(256) void out_k(const float* __restrict__ x, const ushort_t* __restrict__ r,
        const ushort_t* __restrict__ rlow, const ushort_t* __restrict__ wloc, const ushort_t* __restrict__ lrA,
        float* __restrict__ out){
    __shared__ __align__(16) float st[4][16][68];
    int wave = threadIdx.x>>6, lane = threadIdx.x&63;
    int m = lane&15, quad = lane>>4;
    int orow = lane>>2, oq = lane&3;
    int n = blockIdx.y;

    short8 wl[2][4], la[4][2];
    #pragma unroll
    for (int c=0;c<4;++c)
        #pragma unroll
        for (int s=0;s<2;++s){
            wl[s][c] = *(const short8*)(wloc + n*4096 + (c*16+m)*64 + s*32 + quad*8);
            la[c][s] = *(const short8*)(lrA + (size_t)(n*64 + c*16 + m)*64 + s*32 + quad*8);
        }
    #pragma unroll
    for (int t=0;t<2;++t){
        int r0 = blockIdx.x*128 + wave*32 + t*16;
        const float* xb = x + (size_t)(r0+orow)*D_ + n*64;
        float4 xv[4];
        #pragma unroll
        for (int it=0;it<4;++it) xv[it] = *(const float4*)(xb + (it*4+oq)*4);

        const ushort_t* lb = rlow + (size_t)(r0+m)*64 + quad*8;
        short8 al0 = *(const short8*)lb;
        short8 al1 = *(const short8*)(lb + 32);
        const ushort_t* ab = r + (size_t)(r0+m)*D_ + n*64 + quad*8;
        short8 ar0 = *(const short8*)ab;
        short8 ar1 = *(const short8*)(ab + 32);
        f32x4 acc[4];
        #pragma unroll
        for (int c=0;c<4;++c){
            acc[c]=(f32x4)0.f;
            acc[c]=mfma16(al0, la[c][0], acc[c]);
            acc[c]=mfma16(al1, la[c][1], acc[c]);
            acc[c]=mfma16(ar0, wl[0][c], acc[c]);
            acc[c]=mfma16(ar1, wl[1][c], acc[c]);
        }
        #pragma unroll
        for (int c=0;c<4;++c)
            #pragma unroll
            for (int r2=0;r2<4;++r2)
                st[wave][quad*4+r2][c*16+m] = acc[c][r2];
        float* ob = out + (size_t)(r0+orow)*D_ + n*64;
        #pragma unroll
        for (int it=0;it<4;++it){
            float4 v = *(const float4*)&st[wave][orow][(it*4+oq)*4];
            v.x += xv[it].x; v.y += xv[it].y; v.z += xv[it].z; v.w += xv[it].w;
            *(float4*)(ob + (it*4+oq)*4) = v;
        }
    }
}

extern "C" void kernel_launch(void* const* d_in, const int* in_sizes, int n_in,
                              void* d_out, int out_size, void* d_ws, size_t ws_size,
                              hipStream_t stream) {
    const float* x         = (const float*)d_in[0];
    const int*   active_k  = (const int*)  d_in[1];
    const float* b_seq_w   = (const float*)d_in[2];
    const float* b_depth_w = (const float*)d_in[3];
    const float* w_post_w  = (const float*)d_in[4];
    const float* w_local_w = (const float*)d_in[5];
    const float* lr_A      = (const float*)d_in[6];
    const float* lr_B      = (const float*)d_in[7];
    const float* logA_seq  = (const float*)d_in[8];
    const float* logdt_seq = (const float*)d_in[9];
    const float* logA_dep  = (const float*)d_in[10];
    const float* logdt_dep = (const float*)d_in[11];

    float* ws      = (float*)d_ws;
    float* carry   = ws;                             // B_*NCH_*D_ = 262144
    float* aseq    = carry + (size_t)B_*NCH_*D_;
    float* apowC   = aseq + D_;
    float* gain    = apowC + D_;
    float* apowtab = gain + D_;                      // CHUNK_*D_ = 65536
    ushort_t* ub       = (ushort_t*)(apowtab + (size_t)CHUNK_*D_);
    ushort_t* e_bf     = ub;                         // R_*D_
    ushort_t* hsum_bf  = e_bf + (size_t)R_*D_;       // R_*D_ (scanned drive + hdep)
    ushort_t* hn_bf    = hsum_bf + (size_t)R_*D_;    // R_*D_ (normalized h)
    ushort_t* r_bf     = hn_bf + (size_t)R_*D_;      // R_*D_
    ushort_t* rlow_bf  = r_bf + (size_t)R_*D_;       // R_*64
    ushort_t* wseq_bf  = rlow_bf + (size_t)R_*64;    // 65536
    ushort_t* wdep_bf  = wseq_bf + 65536;
    ushort_t* wpost_bf = wdep_bf + 65536;            // 196608
    ushort_t* wloc_bf  = wpost_bf + 196608;
    ushort_t* lrA_bf   = wloc_bf + 65536;
    ushort_t* lrB_bf   = lrA_bf + 65536;

    prep_k<<<(524288 + D_ + 255)/256, 256, 0, stream>>>(
        b_seq_w, b_depth_w, w_post_w, w_local_w, lr_A, lr_B,
        wseq_bf, wdep_bf, wpost_bf, wloc_bf, lrA_bf, lrB_bf,
        logA_seq, logdt_seq, logA_dep, logdt_dep, active_k, aseq, apowC, gain, apowtab);

    rmsbf_k <<<R_, 256, 0, stream>>>(x, e_bf);
    bd2s_k  <<<dim3(R_/256, 16), 256, 0, stream>>>(e_bf, wseq_bf, wdep_bf, gain, aseq,
                                                   hsum_bf, carry);
    scan2_k <<<(B_*D_)/256, 256, 0, stream>>>(carry, apowC);
    scan3s_k<<<R_/8, 256, 0, stream>>>(hsum_bf, aseq, carry, apowtab, hn_bf);
    post_k  <<<dim3(R_/128, 16), 256, 0, stream>>>(hn_bf, e_bf, wpost_bf, r_bf);
    rlow_k  <<<R_/16, 256, 0, stream>>>(r_bf, lrB_bf, rlow_bf);
    out_k   <<<dim3(R_/128, 16), 256, 0, stream>>>(x, r_bf, rlow_bf, wloc_bf, lrA_bf, (float*)d_out);
}

// Round 10
// 285.491 us; speedup vs baseline: 1.0862x; 1.0802x over previous
//
#include <hip/hip_runtime.h>

#define B_ 4
#define T_ 4096
#define D_ 1024
#define R_ (B_*T_)
#define CHUNK_ 64
#define NCH_ (T_/CHUNK_)
#define EPS_ 1.1920929e-07f

typedef unsigned short ushort_t;
typedef __attribute__((ext_vector_type(8))) short short8;
typedef __attribute__((ext_vector_type(4))) float f32x4;

__device__ __forceinline__ float silu_f(float v){ return v / (1.0f + __expf(-v)); }

__device__ __forceinline__ ushort_t f2bf(float f){
    unsigned u = __float_as_uint(f);
    unsigned r = u + 0x7fffu + ((u>>16)&1u);
    return (ushort_t)(r>>16);
}
__device__ __forceinline__ float bf2f(ushort_t s){ return __uint_as_float(((unsigned)s)<<16); }

__device__ __forceinline__ f32x4 mfma16(short8 a, short8 b, f32x4 c){
    return __builtin_amdgcn_mfma_f32_16x16x32_bf16(a, b, c, 0, 0, 0);
}

// ---------------- prep: weight cvt (bf16) + scalar setup + apow table ----------------
__global__ void prep_k(const float* __restrict__ s0, const float* __restrict__ s1,
                       const float* __restrict__ s2, const float* __restrict__ s3,
                       const float* __restrict__ s4, const float* __restrict__ s5,
                       ushort_t* __restrict__ d0, ushort_t* __restrict__ d1,
                       ushort_t* __restrict__ d2, ushort_t* __restrict__ d3,
                       ushort_t* __restrict__ d4, ushort_t* __restrict__ d5,
                       const float* __restrict__ logA_seq, const float* __restrict__ logdt_seq,
                       const float* __restrict__ logA_dep, const float* __restrict__ logdt_dep,
                       const int* __restrict__ active_k,
                       float* __restrict__ aseq, float* __restrict__ apowC,
                       float* __restrict__ gain, float* __restrict__ apowtab){
    int i = blockIdx.x*256 + threadIdx.x;
    if      (i < 65536)   d0[i] = f2bf(s0[i]);
    else if (i < 131072)  d1[i-65536] = f2bf(s1[i-65536]);
    else if (i < 327680)  d2[i-131072] = f2bf(s2[i-131072]);
    else if (i < 393216)  d3[i-327680] = f2bf(s3[i-327680]);
    else if (i < 458752)  d4[i-393216] = f2bf(s4[i-393216]);
    else if (i < 524288)  d5[i-458752] = f2bf(s5[i-458752]);
    else if (i < 524288 + D_){
        int d = i - 524288;
        float K = (float)(*active_k);
        float a = expf(-expf(logA_seq[d]) * expf(logdt_seq[d]));
        a = fmaxf(a, 1e-6f);
        aseq[d] = a;
        apowC[d] = powf(a, (float)CHUNK_);
        // apowtab[s][d] = a^(s+1), s = row index within 64-chunk
        float ap = a;
        for (int s2=0;s2<CHUNK_;++s2){ apowtab[s2*D_ + d] = ap; ap *= a; }
        float g;
        if (d < 128) {
            g = K;
        } else {
            float ad = expf(-expf(logA_dep[d-128]) * expf(logdt_dep[d-128]));
            float om = 1.0f - ad;
            if (fabsf(om) < 1e-6f) g = K;
            else g = (1.0f - powf(ad, K)) / fmaxf(om, 1e-8f);
        }
        gain[d] = g;
    }
}

// ---------------- rms_norm(x) -> e bf16 ----------------
__global__ __launch_bounds__(256) void rmsbf_k(const float* __restrict__ x, ushort_t* __restrict__ e){
    int row = blockIdx.x;
    int tid = threadIdx.x;
    float4 v = ((const float4*)(x + (size_t)row*D_))[tid];
    float ss = v.x*v.x + v.y*v.y + v.z*v.z + v.w*v.w;
    for (int off=32; off; off>>=1) ss += __shfl_down(ss, off, 64);
    __shared__ float red[4];
    if ((tid&63)==0) red[tid>>6] = ss;
    __syncthreads();
    float tot = red[0]+red[1]+red[2]+red[3];
    float scale = 1.0f / sqrtf(tot*(1.0f/D_) + EPS_);
    ushort4 o;
    o.x = f2bf(v.x*scale); o.y = f2bf(v.y*scale); o.z = f2bf(v.z*scale); o.w = f2bf(v.w*scale);
    ((ushort4*)(e + (size_t)row*D_))[tid] = o;
}

// ---------------- bd2s: blockdiags + fused local chunk scan ----------------
__global__ __launch_bounds__(256) void bd2s_k(const ushort_t* __restrict__ e,
        const ushort_t* __restrict__ wseq, const ushort_t* __restrict__ wdep,
        const float* __restrict__ gain, const float* __restrict__ aseq,
        ushort_t* __restrict__ hsum, float* __restrict__ carry){
    __shared__ __align__(16) ushort_t sd[4][16][72];
    __shared__ __align__(16) ushort_t sh[4][16][72];
    int wave = threadIdx.x>>6, lane = threadIdx.x&63;
    int m = lane&15, quad = lane>>4;
    int orow = lane>>2, oq = lane&3;
    int n = blockIdx.y;
    int chunk0 = blockIdx.x*256 + wave*64;

    short8 bs[2][4], bd[2][4];
    #pragma unroll
    for (int s=0;s<2;++s)
        #pragma unroll
        for (int c=0;c<4;++c){
            bs[s][c] = *(const short8*)(wseq + n*4096 + (c*16+m)*64 + s*32 + quad*8);
            bd[s][c] = *(const short8*)(wdep + n*4096 + (c*16+m)*64 + s*32 + quad*8);
        }
    float g[4];
    #pragma unroll
    for (int c=0;c<4;++c) g[c] = gain[n*64 + c*16 + m];

    float a = aseq[n*64 + lane];
    float hh = 0.f;

    #pragma unroll
    for (int t=0;t<4;++t){
        int r0 = chunk0 + t*16;
        const ushort_t* ab = e + (size_t)(r0+m)*D_ + n*64 + quad*8;
        short8 a0 = *(const short8*)ab;
        short8 a1 = *(const short8*)(ab + 32);
        f32x4 accs[4], accd[4];
        #pragma unroll
        for (int c=0;c<4;++c){
            accs[c]=(f32x4)0.f; accd[c]=(f32x4)0.f;
            accs[c]=mfma16(a0, bs[0][c], accs[c]);
            accd[c]=mfma16(a0, bd[0][c], accd[c]);
            accs[c]=mfma16(a1, bs[1][c], accs[c]);
            accd[c]=mfma16(a1, bd[1][c], accd[c]);
        }
        #pragma unroll
        for (int c=0;c<4;++c)
            #pragma unroll
            for (int r=0;r<4;++r){
                sd[wave][quad*4+r][c*16+m] = f2bf(silu_f(accs[c][r]));
                sh[wave][quad*4+r][c*16+m] = f2bf(g[c]*silu_f(accd[c][r]));
            }
        #pragma unroll
        for (int s=0;s<16;++s){
            hh = fmaf(a, hh, bf2f(sd[wave][s][lane]));
            sd[wave][s][lane] = f2bf(hh + bf2f(sh[wave][s][lane]));
        }
        ushort_t* db = hsum + (size_t)(r0+orow)*D_ + n*64;
        #pragma unroll
        for (int it=0;it<2;++it)
            *(short8*)(db + (it*4+oq)*8) = *(const short8*)&sd[wave][orow][(it*4+oq)*8];
    }
    carry[(size_t)(chunk0>>6)*D_ + n*64 + lane] = hh;
}

// ---------------- scan2: serial prefix over chunk carries ----------------
__global__ __launch_bounds__(256) void scan2_k(float* __restrict__ carry, const float* __restrict__ apowC){
    int tid = blockIdx.x*256 + threadIdx.x;      // B_*D_ threads
    int d = tid & (D_-1);
    int b = tid >> 10;
    float aC = apowC[d];
    float pref = 0.f;
    for (int c=0;c<NCH_;++c){
        size_t idx = (size_t)(b*NCH_+c)*D_ + d;
        float s = carry[idx];
        carry[idx] = pref;
        pref = fmaf(aC, pref, s);
    }
}

// ---------------- scan3s: hn = rmsnorm(hsum + P*a^(s+1)) in ONE pass ----------------
__global__ __launch_bounds__(256) void scan3s_k(const ushort_t* __restrict__ hsum,
                                                const float* __restrict__ aseq,
                                                const float* __restrict__ carry,
                                                const float* __restrict__ apowtab,
                                                ushort_t* __restrict__ hn){
    __shared__ float part[4][4];
    __shared__ float scl[8];
    int tid = threadIdx.x;
    int lane = tid & 63, wave = tid >> 6;
    int cg = tid & 127;        // col group (8 cols)
    int rp = tid >> 7;         // row parity (0/1)
    int d0 = cg*8;
    int row0 = blockIdx.x*8;   // 8 rows, all within one 64-chunk
    int bc = row0 >> 6;
    int s0 = row0 & 63;

    float a2[8], P[8], apow[8];
    #pragma unroll
    for (int j=0;j<8;++j){
        float aj = aseq[d0+j];
        a2[j] = aj*aj;
        P[j]  = carry[(size_t)bc*D_ + d0 + j];
        apow[j] = apowtab[(size_t)(s0 + rp)*D_ + d0 + j];   // a^(s+1) at first row
    }

    float hf[4][8];
    #pragma unroll
    for (int i=0;i<4;++i){
        int row = row0 + i*2 + rp;
        short8 v = *(const short8*)(hsum + (size_t)row*D_ + d0);
        float ss = 0.f;
        #pragma unroll
        for (int j=0;j<8;++j){
            float f = bf2f((ushort_t)v[j]) + P[j]*apow[j];
            hf[i][j] = f;
            ss += f*f;
            apow[j] *= a2[j];
        }
        for (int off=32; off; off>>=1) ss += __shfl_down(ss, off, 64);
        if (lane==0) part[wave][i] = ss;
    }
    __syncthreads();
    if (tid < 8){
        int r = tid;                 // row index within block
        int rr = r & 1, ii = r >> 1;
        float sum = part[rr*2][ii] + part[rr*2+1][ii];
        scl[r] = rsqrtf(sum*(1.0f/D_) + EPS_);
    }
    __syncthreads();
    #pragma unroll
    for (int i=0;i<4;++i){
        int rloc = i*2 + rp;
        float sc = scl[rloc];
        short8 o;
        #pragma unroll
        for (int j=0;j<8;++j) o[j] = (short)f2bf(hf[i][j]*sc);
        *(short8*)(hn + (size_t)(row0 + rloc)*D_ + d0) = o;
    }
}

// ---------------- post: r = silu(concat[hn,e,eshift] @ wpost^T) bf16 ----------------
// ILP experiment, attempt 3: af[2][6] preloaded upfront; s-loop FULLY unrolled
// so every af index is compile-time constant (rule #20: runtime-indexed
// ext_vector arrays go to scratch -- this, not the register budget, caused
// R8/R9's 131MB spill traffic). launch_bounds(256,4) = 128-VGPR budget.
__global__ __launch_bounds__(256, 4) void post_k(const ushort_t* __restrict__ hn,
                                              const ushort_t* __restrict__ e,
                                              const ushort_t* __restrict__ wpost, ushort_t* __restrict__ rout){
    __shared__ __align__(16) ushort_t st[4][16][72];
    int wave = threadIdx.x>>6, lane = threadIdx.x&63;
    int m = lane&15, quad = lane>>4;
    int orow = lane>>2, oq = lane&3;
    int n = blockIdx.y;
    int row0 = blockIdx.x*128 + wave*32 + m;

    short8 af[2][6];
    #pragma unroll
    for (int t=0;t<2;++t){
        int row = row0 + t*16;
        #pragma unroll
        for (int s=0;s<6;++s){
            int g0 = n*192 + s*32;
            if (g0 < 1024){
                af[t][s] = *(const short8*)(hn + (size_t)row*D_ + g0 + quad*8);
            } else if (g0 < 2048){
                af[t][s] = *(const short8*)(e + (size_t)row*D_ + (g0-1024) + quad*8);
            } else {
                if ((row & (T_-1)) == 0) af[t][s] = short8{0,0,0,0,0,0,0,0};
                else af[t][s] = *(const short8*)(e + (size_t)(row-1)*D_ + (g0-2048) + quad*8);
            }
        }
    }

    f32x4 acc[2][4];
    #pragma unroll
    for (int t=0;t<2;++t)
        #pragma unroll
        for (int c=0;c<4;++c) acc[t][c]=(f32x4)0.f;

    #pragma unroll
    for (int s=0;s<6;++s){
        short8 bw[4];
        #pragma unroll
        for (int c=0;c<4;++c)
            bw[c] = *(const short8*)(wpost + n*(64*192) + (c*16+m)*192 + s*32 + quad*8);
        #pragma unroll
        for (int t=0;t<2;++t)
            #pragma unroll
            for (int c=0;c<4;++c)
                acc[t][c] = mfma16(af[t][s], bw[c], acc[t][c]);
    }
    #pragma unroll
    for (int t=0;t<2;++t){
        int r0 = blockIdx.x*128 + wave*32 + t*16;
        #pragma unroll
        for (int c=0;c<4;++c)
            #pragma unroll
            for (int r=0;r<4;++r)
                st[wave][quad*4+r][c*16+m] = f2bf(silu_f(acc[t][c][r]));
        ushort_t* db = rout + (size_t)(r0+orow)*D_ + n*64;
        #pragma unroll
        for (int it=0;it<2;++it)
            *(short8*)(db + (it*4+oq)*8) = *(const short8*)&st[wave][orow][(it*4+oq)*8];
    }
}

// ---------------- rlow = r @ lrB^T (K=1024 -> 64) bf16, split-K over 4 waves ----------------
__global__ __launch_bounds__(256) void rlow_k(const ushort_t* __restrict__ r, const ushort_t* __restrict__ lrB,
                                              ushort_t* __restrict__ rlow){
    __shared__ __align__(16) float sacc[4][16][68];
    int wave = threadIdx.x>>6, lane = threadIdx.x&63;
    int m = lane&15, quad = lane>>4;
    int r0 = blockIdx.x*16;
    const ushort_t* ab = r + (size_t)(r0+m)*D_ + wave*256 + quad*8;
    short8 a[8];
    #pragma unroll
    for (int s=0;s<8;++s) a[s] = *(const short8*)(ab + s*32);
    f32x4 acc[4];
    #pragma unroll
    for (int c=0;c<4;++c) acc[c]=(f32x4)0.f;
    #pragma unroll
    for (int s=0;s<8;++s){
        #pragma unroll
        for (int c=0;c<4;++c){
            short8 b = *(const short8*)(lrB + (c*16+m)*1024 + wave*256 + s*32 + quad*8);
            acc[c] = mfma16(a[s], b, acc[c]);
        }
    }
    #pragma unroll
    for (int c=0;c<4;++c)
        #pragma unroll
        for (int r2=0;r2<4;++r2)
            sacc[wave][quad*4+r2][c*16+m] = acc[c][r2];
    __syncthreads();
    int row  = threadIdx.x>>4;        // 0..15
    int col4 = (threadIdx.x&15)*4;    // 0..60 step 4
    float4 v0 = *(const float4*)&sacc[0][row][col4];
    float4 v1 = *(const float4*)&sacc[1][row][col4];
    float4 v2 = *(const float4*)&sacc[2][row][col4];
    float4 v3 = *(const float4*)&sacc[3][row][col4];
    ushort4 o;
    o.x = f2bf(v0.x+v1.x+v2.x+v3.x);
    o.y = f2bf(v0.y+v1.y+v2.y+v3.y);
    o.z = f2bf(v0.z+v1.z+v2.z+v3.z);
    o.w = f2bf(v0.w+v1.w+v2.w+v3.w);
    *(ushort4*)(rlow + (size_t)(r0+row)*64 + col4) = o;
}

// ---------------- out = x + r@wloc^T + rlow@lrA^T ----------------
__global__ __launch_bounds__(256) void out_k(const float* __restrict__ x, const ushort_t* __restrict__ r,
        const ushort_t* __restrict__ rlow, const ushort_t* __restrict__ wloc, const ushort_t* __restrict__ lrA,
        float* __restrict__ out){
    __shared__ __align__(16) float st[4][16][68];
    int wave = threadIdx.x>>6, lane = threadIdx.x&63;
    int m = lane&15, quad = lane>>4;
    int orow = lane>>2, oq = lane&3;
    int n = blockIdx.y;

    short8 wl[2][4], la[4][2];
    #pragma unroll
    for (int c=0;c<4;++c)
        #pragma unroll
        for (int s=0;s<2;++s){
            wl[s][c] = *(const short8*)(wloc + n*4096 + (c*16+m)*64 + s*32 + quad*8);
            la[c][s] = *(const short8*)(lrA + (size_t)(n*64 + c*16 + m)*64 + s*32 + quad*8);
        }
    #pragma unroll
    for (int t=0;t<2;++t){
        int r0 = blockIdx.x*128 + wave*32 + t*16;
        const float* xb = x + (size_t)(r0+orow)*D_ + n*64;
        float4 xv[4];
        #pragma unroll
        for (int it=0;it<4;++it) xv[it] = *(const float4*)(xb + (it*4+oq)*4);

        const ushort_t* lb = rlow + (size_t)(r0+m)*64 + quad*8;
        short8 al0 = *(const short8*)lb;
        short8 al1 = *(const short8*)(lb + 32);
        const ushort_t* ab = r + (size_t)(r0+m)*D_ + n*64 + quad*8;
        short8 ar0 = *(const short8*)ab;
        short8 ar1 = *(const short8*)(ab + 32);
        f32x4 acc[4];
        #pragma unroll
        for (int c=0;c<4;++c){
            acc[c]=(f32x4)0.f;
            acc[c]=mfma16(al0, la[c][0], acc[c]);
            acc[c]=mfma16(al1, la[c][1], acc[c]);
            acc[c]=mfma16(ar0, wl[0][c], acc[c]);
            acc[c]=mfma16(ar1, wl[1][c], acc[c]);
        }
        #pragma unroll
        for (int c=0;c<4;++c)
            #pragma unroll
            for (int r2=0;r2<4;++r2)
                st[wave][quad*4+r2][c*16+m] = acc[c][r2];
        float* ob = out + (size_t)(r0+orow)*D_ + n*64;
        #pragma unroll
        for (int it=0;it<4;++it){
            float4 v = *(const float4*)&st[wave][orow][(it*4+oq)*4];
            v.x += xv[it].x; v.y += xv[it].y; v.z += xv[it].z; v.w += xv[it].w;
            *(float4*)(ob + (it*4+oq)*4) = v;
        }
    }
}

extern "C" void kernel_launch(void* const* d_in, const int* in_sizes, int n_in,
                              void* d_out, int out_size, void* d_ws, size_t ws_size,
                              hipStream_t stream) {
    const float* x         = (const float*)d_in[0];
    const int*   active_k  = (const int*)  d_in[1];
    const float* b_seq_w   = (const float*)d_in[2];
    const float* b_depth_w = (const float*)d_in[3];
    const float* w_post_w  = (const float*)d_in[4];
    const float* w_local_w = (const float*)d_in[5];
    const float* lr_A      = (const float*)d_in[6];
    const float* lr_B      = (const float*)d_in[7];
    const float* logA_seq  = (const float*)d_in[8];
    const float* logdt_seq = (const float*)d_in[9];
    const float* logA_dep  = (const float*)d_in[10];
    const float* logdt_dep = (const float*)d_in[11];

    float* ws      = (float*)d_ws;
    float* carry   = ws;                             // B_*NCH_*D_ = 262144
    float* aseq    = carry + (size_t)B_*NCH_*D_;
    float* apowC   = aseq + D_;
    float* gain    = apowC + D_;
    float* apowtab = gain + D_;                      // CHUNK_*D_ = 65536
    ushort_t* ub       = (ushort_t*)(apowtab + (size_t)CHUNK_*D_);
    ushort_t* e_bf     = ub;                         // R_*D_
    ushort_t* hsum_bf  = e_bf + (size_t)R_*D_;       // R_*D_ (scanned drive + hdep)
    ushort_t* hn_bf    = hsum_bf + (size_t)R_*D_;    // R_*D_ (normalized h)
    ushort_t* r_bf     = hn_bf + (size_t)R_*D_;      // R_*D_
    ushort_t* rlow_bf  = r_bf + (size_t)R_*D_;       // R_*64
    ushort_t* wseq_bf  = rlow_bf + (size_t)R_*64;    // 65536
    ushort_t* wdep_bf  = wseq_bf + 65536;
    ushort_t* wpost_bf = wdep_bf + 65536;            // 196608
    ushort_t* wloc_bf  = wpost_bf + 196608;
    ushort_t* lrA_bf   = wloc_bf + 65536;
    ushort_t* lrB_bf   = lrA_bf + 65536;

    prep_k<<<(524288 + D_ + 255)/256, 256, 0, stream>>>(
        b_seq_w, b_depth_w, w_post_w, w_local_w, lr_A, lr_B,
        wseq_bf, wdep_bf, wpost_bf, wloc_bf, lrA_bf, lrB_bf,
        logA_seq, logdt_seq, logA_dep, logdt_dep, active_k, aseq, apowC, gain, apowtab);

    rmsbf_k <<<R_, 256, 0, stream>>>(x, e_bf);
    bd2s_k  <<<dim3(R_/256, 16), 256, 0, stream>>>(e_bf, wseq_bf, wdep_bf, gain, aseq,
                                                   hsum_bf, carry);
    scan2_k <<<(B_*D_)/256, 256, 0, stream>>>(carry, apowC);
    scan3s_k<<<R_/8, 256, 0, stream>>>(hsum_bf, aseq, carry, apowtab, hn_bf);
    post_k  <<<dim3(R_/128, 16), 256, 0, stream>>>(hn_bf, e_bf, wpost_bf, r_bf);
    rlow_k  <<<R_/16, 256, 0, stream>>>(r_bf, lrB_bf, rlow_bf);
    out_k   <<<dim3(R_/128, 16), 256, 0, stream>>>(x, r_bf, rlow_bf, wloc_bf, lrA_bf, (float*)d_out);
}

// Round 11
// 280.121 us; speedup vs baseline: 1.1071x; 1.0192x over previous
//
#include <hip/hip_runtime.h>

#define B_ 4
#define T_ 4096
#define D_ 1024
#define R_ (B_*T_)
#define CHUNK_ 64
#define NCH_ (T_/CHUNK_)
#define EPS_ 1.1920929e-07f

typedef unsigned short ushort_t;
typedef __attribute__((ext_vector_type(8))) short short8;
typedef __attribute__((ext_vector_type(4))) float f32x4;

__device__ __forceinline__ float silu_f(float v){ return v / (1.0f + __expf(-v)); }

__device__ __forceinline__ ushort_t f2bf(float f){
    unsigned u = __float_as_uint(f);
    unsigned r = u + 0x7fffu + ((u>>16)&1u);
    return (ushort_t)(r>>16);
}
__device__ __forceinline__ float bf2f(ushort_t s){ return __uint_as_float(((unsigned)s)<<16); }

__device__ __forceinline__ f32x4 mfma16(short8 a, short8 b, f32x4 c){
    return __builtin_amdgcn_mfma_f32_16x16x32_bf16(a, b, c, 0, 0, 0);
}

// ---------------- prep: weight cvt (bf16) + scalar setup + apow table ----------------
__global__ void prep_k(const float* __restrict__ s0, const float* __restrict__ s1,
                       const float* __restrict__ s2, const float* __restrict__ s3,
                       const float* __restrict__ s4, const float* __restrict__ s5,
                       ushort_t* __restrict__ d0, ushort_t* __restrict__ d1,
                       ushort_t* __restrict__ d2, ushort_t* __restrict__ d3,
                       ushort_t* __restrict__ d4, ushort_t* __restrict__ d5,
                       const float* __restrict__ logA_seq, const float* __restrict__ logdt_seq,
                       const float* __restrict__ logA_dep, const float* __restrict__ logdt_dep,
                       const int* __restrict__ active_k,
                       float* __restrict__ aseq, float* __restrict__ apowC,
                       float* __restrict__ gain, float* __restrict__ apowtab){
    int i = blockIdx.x*256 + threadIdx.x;
    if      (i < 65536)   d0[i] = f2bf(s0[i]);
    else if (i < 131072)  d1[i-65536] = f2bf(s1[i-65536]);
    else if (i < 327680)  d2[i-131072] = f2bf(s2[i-131072]);
    else if (i < 393216)  d3[i-327680] = f2bf(s3[i-327680]);
    else if (i < 458752)  d4[i-393216] = f2bf(s4[i-393216]);
    else if (i < 524288)  d5[i-458752] = f2bf(s5[i-458752]);
    else if (i < 524288 + D_){
        int d = i - 524288;
        float K = (float)(*active_k);
        float a = expf(-expf(logA_seq[d]) * expf(logdt_seq[d]));
        a = fmaxf(a, 1e-6f);
        aseq[d] = a;
        apowC[d] = powf(a, (float)CHUNK_);
        // apowtab[s][d] = a^(s+1), s = row index within 64-chunk
        float ap = a;
        for (int s2=0;s2<CHUNK_;++s2){ apowtab[s2*D_ + d] = ap; ap *= a; }
        float g;
        if (d < 128) {
            g = K;
        } else {
            float ad = expf(-expf(logA_dep[d-128]) * expf(logdt_dep[d-128]));
            float om = 1.0f - ad;
            if (fabsf(om) < 1e-6f) g = K;
            else g = (1.0f - powf(ad, K)) / fmaxf(om, 1e-8f);
        }
        gain[d] = g;
    }
}

// ---------------- rms_norm(x) -> e bf16, one wave per row (no LDS, no barrier) ----------------
__global__ __launch_bounds__(256) void rmsbf_k(const float* __restrict__ x, ushort_t* __restrict__ e){
    int wave = threadIdx.x>>6, lane = threadIdx.x&63;
    int row = blockIdx.x*4 + wave;
    const float* xr = x + (size_t)row*D_;
    float4 v[4];
    #pragma unroll
    for (int k=0;k<4;++k) v[k] = ((const float4*)xr)[lane + k*64];
    float ss = 0.f;
    #pragma unroll
    for (int k=0;k<4;++k) ss += v[k].x*v[k].x + v[k].y*v[k].y + v[k].z*v[k].z + v[k].w*v[k].w;
    for (int off=32; off; off>>=1) ss += __shfl_down(ss, off, 64);
    ss = __shfl(ss, 0, 64);
    float scale = 1.0f / sqrtf(ss*(1.0f/D_) + EPS_);
    ushort_t* er = e + (size_t)row*D_;
    #pragma unroll
    for (int k=0;k<4;++k){
        ushort4 o;
        o.x = f2bf(v[k].x*scale); o.y = f2bf(v[k].y*scale);
        o.z = f2bf(v[k].z*scale); o.w = f2bf(v[k].w*scale);
        ((ushort4*)er)[lane + k*64] = o;
    }
}

// ---------------- bd2s: blockdiags + fused local chunk scan ----------------
__global__ __launch_bounds__(256) void bd2s_k(const ushort_t* __restrict__ e,
        const ushort_t* __restrict__ wseq, const ushort_t* __restrict__ wdep,
        const float* __restrict__ gain, const float* __restrict__ aseq,
        ushort_t* __restrict__ hsum, float* __restrict__ carry){
    __shared__ __align__(16) ushort_t sd[4][16][72];
    __shared__ __align__(16) ushort_t sh[4][16][72];
    int wave = threadIdx.x>>6, lane = threadIdx.x&63;
    int m = lane&15, quad = lane>>4;
    int orow = lane>>2, oq = lane&3;
    int n = blockIdx.y;
    int chunk0 = blockIdx.x*256 + wave*64;

    short8 bs[2][4], bd[2][4];
    #pragma unroll
    for (int s=0;s<2;++s)
        #pragma unroll
        for (int c=0;c<4;++c){
            bs[s][c] = *(const short8*)(wseq + n*4096 + (c*16+m)*64 + s*32 + quad*8);
            bd[s][c] = *(const short8*)(wdep + n*4096 + (c*16+m)*64 + s*32 + quad*8);
        }
    float g[4];
    #pragma unroll
    for (int c=0;c<4;++c) g[c] = gain[n*64 + c*16 + m];

    float a = aseq[n*64 + lane];
    float hh = 0.f;

    #pragma unroll
    for (int t=0;t<4;++t){
        int r0 = chunk0 + t*16;
        const ushort_t* ab = e + (size_t)(r0+m)*D_ + n*64 + quad*8;
        short8 a0 = *(const short8*)ab;
        short8 a1 = *(const short8*)(ab + 32);
        f32x4 accs[4], accd[4];
        #pragma unroll
        for (int c=0;c<4;++c){
            accs[c]=(f32x4)0.f; accd[c]=(f32x4)0.f;
            accs[c]=mfma16(a0, bs[0][c], accs[c]);
            accd[c]=mfma16(a0, bd[0][c], accd[c]);
            accs[c]=mfma16(a1, bs[1][c], accs[c]);
            accd[c]=mfma16(a1, bd[1][c], accd[c]);
        }
        #pragma unroll
        for (int c=0;c<4;++c)
            #pragma unroll
            for (int r=0;r<4;++r){
                sd[wave][quad*4+r][c*16+m] = f2bf(silu_f(accs[c][r]));
                sh[wave][quad*4+r][c*16+m] = f2bf(g[c]*silu_f(accd[c][r]));
            }
        #pragma unroll
        for (int s=0;s<16;++s){
            hh = fmaf(a, hh, bf2f(sd[wave][s][lane]));
            sd[wave][s][lane] = f2bf(hh + bf2f(sh[wave][s][lane]));
        }
        ushort_t* db = hsum + (size_t)(r0+orow)*D_ + n*64;
        #pragma unroll
        for (int it=0;it<2;++it)
            *(short8*)(db + (it*4+oq)*8) = *(const short8*)&sd[wave][orow][(it*4+oq)*8];
    }
    carry[(size_t)(chunk0>>6)*D_ + n*64 + lane] = hh;
}

// ---------------- scan2: serial prefix over chunk carries ----------------
// Preload all 64 carries into registers (independent loads, one wait), then
// register-serial scan + stores. Was: 64 dependent L2 round-trips per thread,
// 16 blocks. Now: 64 blocks x 64 threads, one latency exposure.
__global__ __launch_bounds__(64) void scan2_k(float* __restrict__ carry, const float* __restrict__ apowC){
    int tid = blockIdx.x*64 + threadIdx.x;       // B_*D_ threads
    int d = tid & (D_-1);
    int b = tid >> 10;
    float aC = apowC[d];
    float s[NCH_];
    #pragma unroll
    for (int c=0;c<NCH_;++c) s[c] = carry[(size_t)(b*NCH_+c)*D_ + d];
    float pref = 0.f;
    #pragma unroll
    for (int c=0;c<NCH_;++c){
        float cur = s[c];
        carry[(size_t)(b*NCH_+c)*D_ + d] = pref;
        pref = fmaf(aC, pref, cur);
    }
}

// ---------------- scan3s: hn = rmsnorm(hsum + P*a^(s+1)) in ONE pass ----------------
__global__ __launch_bounds__(256) void scan3s_k(const ushort_t* __restrict__ hsum,
                                                const float* __restrict__ aseq,
                                                const float* __restrict__ carry,
                                                const float* __restrict__ apowtab,
                                                ushort_t* __restrict__ hn){
    __shared__ float part[4][4];
    __shared__ float scl[8];
    int tid = threadIdx.x;
    int lane = tid & 63, wave = tid >> 6;
    int cg = tid & 127;        // col group (8 cols)
    int rp = tid >> 7;         // row parity (0/1)
    int d0 = cg*8;
    int row0 = blockIdx.x*8;   // 8 rows, all within one 64-chunk
    int bc = row0 >> 6;
    int s0 = row0 & 63;

    float a2[8], P[8], apow[8];
    #pragma unroll
    for (int j=0;j<8;++j){
        float aj = aseq[d0+j];
        a2[j] = aj*aj;
        P[j]  = carry[(size_t)bc*D_ + d0 + j];
        apow[j] = apowtab[(size_t)(s0 + rp)*D_ + d0 + j];   // a^(s+1) at first row
    }

    float hf[4][8];
    #pragma unroll
    for (int i=0;i<4;++i){
        int row = row0 + i*2 + rp;
        short8 v = *(const short8*)(hsum + (size_t)row*D_ + d0);
        float ss = 0.f;
        #pragma unroll
        for (int j=0;j<8;++j){
            float f = bf2f((ushort_t)v[j]) + P[j]*apow[j];
            hf[i][j] = f;
            ss += f*f;
            apow[j] *= a2[j];
        }
        for (int off=32; off; off>>=1) ss += __shfl_down(ss, off, 64);
        if (lane==0) part[wave][i] = ss;
    }
    __syncthreads();
    if (tid < 8){
        int r = tid;                 // row index within block
        int rr = r & 1, ii = r >> 1;
        float sum = part[rr*2][ii] + part[rr*2+1][ii];
        scl[r] = rsqrtf(sum*(1.0f/D_) + EPS_);
    }
    __syncthreads();
    #pragma unroll
    for (int i=0;i<4;++i){
        int rloc = i*2 + rp;
        float sc = scl[rloc];
        short8 o;
        #pragma unroll
        for (int j=0;j<8;++j) o[j] = (short)f2bf(hf[i][j]*sc);
        *(short8*)(hn + (size_t)(row0 + rloc)*D_ + d0) = o;
    }
}

// ---------------- post: r = silu(concat[hn,e,eshift] @ wpost^T) bf16 ----------------
// R7-proven form (44.5us): s-loop outermost, unroll 1, loop-local loads.
// Preload-ILP variants (R8/R9/R10) all hit rule-#20 scratch or regressed.
__global__ __launch_bounds__(256) void post_k(const ushort_t* __restrict__ hn,
                                              const ushort_t* __restrict__ e,
                                              const ushort_t* __restrict__ wpost, ushort_t* __restrict__ rout){
    __shared__ __align__(16) ushort_t st[4][16][72];
    int wave = threadIdx.x>>6, lane = threadIdx.x&63;
    int m = lane&15, quad = lane>>4;
    int orow = lane>>2, oq = lane&3;
    int n = blockIdx.y;
    int row0 = blockIdx.x*128 + wave*32 + m;

    f32x4 acc[2][4];
    #pragma unroll
    for (int t=0;t<2;++t)
        #pragma unroll
        for (int c=0;c<4;++c) acc[t][c]=(f32x4)0.f;

    #pragma unroll 1
    for (int s=0;s<6;++s){
        int g0 = n*192 + s*32;
        short8 bw[4];
        #pragma unroll
        for (int c=0;c<4;++c)
            bw[c] = *(const short8*)(wpost + n*(64*192) + (c*16+m)*192 + s*32 + quad*8);
        #pragma unroll
        for (int t=0;t<2;++t){
            int row = row0 + t*16;
            short8 af;
            if (g0 < 1024){
                af = *(const short8*)(hn + (size_t)row*D_ + g0 + quad*8);
            } else if (g0 < 2048){
                af = *(const short8*)(e + (size_t)row*D_ + (g0-1024) + quad*8);
            } else {
                if ((row & (T_-1)) == 0) af = short8{0,0,0,0,0,0,0,0};
                else af = *(const short8*)(e + (size_t)(row-1)*D_ + (g0-2048) + quad*8);
            }
            #pragma unroll
            for (int c=0;c<4;++c)
                acc[t][c] = mfma16(af, bw[c], acc[t][c]);
        }
    }
    #pragma unroll
    for (int t=0;t<2;++t){
        int r0 = blockIdx.x*128 + wave*32 + t*16;
        #pragma unroll
        for (int c=0;c<4;++c)
            #pragma unroll
            for (int r=0;r<4;++r)
                st[wave][quad*4+r][c*16+m] = f2bf(silu_f(acc[t][c][r]));
        ushort_t* db = rout + (size_t)(r0+orow)*D_ + n*64;
        #pragma unroll
        for (int it=0;it<2;++it)
            *(short8*)(db + (it*4+oq)*8) = *(const short8*)&st[wave][orow][(it*4+oq)*8];
    }
}

// ---------------- rlow = r @ lrB^T (K=1024 -> 64) bf16, split-K over 4 waves ----------------
__global__ __launch_bounds__(256) void rlow_k(const ushort_t* __restrict__ r, const ushort_t* __restrict__ lrB,
                                              ushort_t* __restrict__ rlow){
    __shared__ __align__(16) float sacc[4][16][68];
    int wave = threadIdx.x>>6, lane = threadIdx.x&63;
    int m = lane&15, quad = lane>>4;
    int r0 = blockIdx.x*16;
    f32x4 acc[4];
    #pragma unroll
    for (int c=0;c<4;++c) acc[c]=(f32x4)0.f;
    const ushort_t* ab = r + (size_t)(r0+m)*D_ + wave*256 + quad*8;
    #pragma unroll
    for (int s=0;s<8;++s){
        short8 a = *(const short8*)(ab + s*32);
        #pragma unroll
        for (int c=0;c<4;++c){
            short8 b = *(const short8*)(lrB + (c*16+m)*1024 + wave*256 + s*32 + quad*8);
            acc[c] = mfma16(a, b, acc[c]);
        }
    }
    #pragma unroll
    for (int c=0;c<4;++c)
        #pragma unroll
        for (int r2=0;r2<4;++r2)
            sacc[wave][quad*4+r2][c*16+m] = acc[c][r2];
    __syncthreads();
    int row  = threadIdx.x>>4;        // 0..15
    int col4 = (threadIdx.x&15)*4;    // 0..60 step 4
    float4 v0 = *(const float4*)&sacc[0][row][col4];
    float4 v1 = *(const float4*)&sacc[1][row][col4];
    float4 v2 = *(const float4*)&sacc[2][row][col4];
    float4 v3 = *(const float4*)&sacc[3][row][col4];
    ushort4 o;
    o.x = f2bf(v0.x+v1.x+v2.x+v3.x);
    o.y = f2bf(v0.y+v1.y+v2.y+v3.y);
    o.z = f2bf(v0.z+v1.z+v2.z+v3.z);
    o.w = f2bf(v0.w+v1.w+v2.w+v3.w);
    *(ushort4*)(rlow + (size_t)(r0+row)*64 + col4) = o;
}

// ---------------- out = x + r@wloc^T + rlow@lrA^T ----------------
// rows split 2x more: grid (R/64, 16), each wave one 16-row tile (t-loop gone).
__global__ __launch_bounds__(256) void out_k(const float* __restrict__ x, const ushort_t* __restrict__ r,
        const ushort_t* __restrict__ rlow, const ushort_t* __restrict__ wloc, const ushort_t* __restrict__ lrA,
        float* __restrict__ out){
    __shared__ __align__(16) float st[4][16][68];
    int wave = threadIdx.x>>6, lane = threadIdx.x&63;
    int m = lane&15, quad = lane>>4;
    int orow = lane>>2, oq = lane&3;
    int n = blockIdx.y;
    int r0 = blockIdx.x*64 + wave*16;

    short8 wl[2][4], la[4][2];
    #pragma unroll
    for (int c=0;c<4;++c)
        #pragma unroll
        for (int s=0;s<2;++s){
            wl[s][c] = *(const short8*)(wloc + n*4096 + (c*16+m)*64 + s*32 + quad*8);
            la[c][s] = *(const short8*)(lrA + (size_t)(n*64 + c*16 + m)*64 + s*32 + quad*8);
        }
    const float* xb = x + (size_t)(r0+orow)*D_ + n*64;
    float4 xv[4];
    #pragma unroll
    for (int it=0;it<4;++it) xv[it] = *(const float4*)(xb + (it*4+oq)*4);

    const ushort_t* lb = rlow + (size_t)(r0+m)*64 + quad*8;
    short8 al0 = *(const short8*)lb;
    short8 al1 = *(const short8*)(lb + 32);
    const ushort_t* ab = r + (size_t)(r0+m)*D_ + n*64 + quad*8;
    short8 ar0 = *(const short8*)ab;
    short8 ar1 = *(const short8*)(ab + 32);
    f32x4 acc[4];
    #pragma unroll
    for (int c=0;c<4;++c){
        acc[c]=(f32x4)0.f;
        acc[c]=mfma16(al0, la[c][0], acc[c]);
        acc[c]=mfma16(al1, la[c][1], acc[c]);
        acc[c]=mfma16(ar0, wl[0][c], acc[c]);
        acc[c]=mfma16(ar1, wl[1][c], acc[c]);
    }
    #pragma unroll
    for (int c=0;c<4;++c)
        #pragma unroll
        for (int r2=0;r2<4;++r2)
            st[wave][quad*4+r2][c*16+m] = acc[c][r2];
    float* ob = out + (size_t)(r0+orow)*D_ + n*64;
    #pragma unroll
    for (int it=0;it<4;++it){
        float4 v = *(const float4*)&st[wave][orow][(it*4+oq)*4];
        v.x += xv[it].x; v.y += xv[it].y; v.z += xv[it].z; v.w += xv[it].w;
        *(float4*)(ob + (it*4+oq)*4) = v;
    }
}

extern "C" void kernel_launch(void* const* d_in, const int* in_sizes, int n_in,
                              void* d_out, int out_size, void* d_ws, size_t ws_size,
                              hipStream_t stream) {
    const float* x         = (const float*)d_in[0];
    const int*   active_k  = (const int*)  d_in[1];
    const float* b_seq_w   = (const float*)d_in[2];
    const float* b_depth_w = (const float*)d_in[3];
    const float* w_post_w  = (const float*)d_in[4];
    const float* w_local_w = (const float*)d_in[5];
    const float* lr_A      = (const float*)d_in[6];
    const float* lr_B      = (const float*)d_in[7];
    const float* logA_seq  = (const float*)d_in[8];
    const float* logdt_seq = (const float*)d_in[9];
    const float* logA_dep  = (const float*)d_in[10];
    const float* logdt_dep = (const float*)d_in[11];

    float* ws      = (float*)d_ws;
    float* carry   = ws;                             // B_*NCH_*D_ = 262144
    float* aseq    = carry + (size_t)B_*NCH_*D_;
    float* apowC   = aseq + D_;
    float* gain    = apowC + D_;
    float* apowtab = gain + D_;                      // CHUNK_*D_ = 65536
    ushort_t* ub       = (ushort_t*)(apowtab + (size_t)CHUNK_*D_);
    ushort_t* e_bf     = ub;                         // R_*D_
    ushort_t* hsum_bf  = e_bf + (size_t)R_*D_;       // R_*D_ (scanned drive + hdep)
    ushort_t* hn_bf    = hsum_bf + (size_t)R_*D_;    // R_*D_ (normalized h)
    ushort_t* r_bf     = hn_bf + (size_t)R_*D_;      // R_*D_
    ushort_t* rlow_bf  = r_bf + (size_t)R_*D_;       // R_*64
    ushort_t* wseq_bf  = rlow_bf + (size_t)R_*64;    // 65536
    ushort_t* wdep_bf  = wseq_bf + 65536;
    ushort_t* wpost_bf = wdep_bf + 65536;            // 196608
    ushort_t* wloc_bf  = wpost_bf + 196608;
    ushort_t* lrA_bf   = wloc_bf + 65536;
    ushort_t* lrB_bf   = lrA_bf + 65536;

    prep_k<<<(524288 + D_ + 255)/256, 256, 0, stream>>>(
        b_seq_w, b_depth_w, w_post_w, w_local_w, lr_A, lr_B,
        wseq_bf, wdep_bf, wpost_bf, wloc_bf, lrA_bf, lrB_bf,
        logA_seq, logdt_seq, logA_dep, logdt_dep, active_k, aseq, apowC, gain, apowtab);

    rmsbf_k <<<R_/4, 256, 0, stream>>>(x, e_bf);
    bd2s_k  <<<dim3(R_/256, 16), 256, 0, stream>>>(e_bf, wseq_bf, wdep_bf, gain, aseq,
                                                   hsum_bf, carry);
    scan2_k <<<(B_*D_)/64, 64, 0, stream>>>(carry, apowC);
    scan3s_k<<<R_/8, 256, 0, stream>>>(hsum_bf, aseq, carry, apowtab, hn_bf);
    post_k  <<<dim3(R_/128, 16), 256, 0, stream>>>(hn_bf, e_bf, wpost_bf, r_bf);
    rlow_k  <<<R_/16, 256, 0, stream>>>(r_bf, lrB_bf, rlow_bf);
    out_k   <<<dim3(R_/64, 16), 256, 0, stream>>>(x, r_bf, rlow_bf, wloc_bf, lrA_bf, (float*)d_out);
}

// Round 12
// 279.417 us; speedup vs baseline: 1.1099x; 1.0025x over previous
//
#include <hip/hip_runtime.h>

#define B_ 4
#define T_ 4096
#define D_ 1024
#define R_ (B_*T_)
#define CHUNK_ 64
#define NCH_ (T_/CHUNK_)
#define EPS_ 1.1920929e-07f

typedef unsigned short ushort_t;
typedef __attribute__((ext_vector_type(8))) short short8;
typedef __attribute__((ext_vector_type(4))) float f32x4;

__device__ __forceinline__ float silu_f(float v){ return v / (1.0f + __expf(-v)); }

__device__ __forceinline__ ushort_t f2bf(float f){
    unsigned u = __float_as_uint(f);
    unsigned r = u + 0x7fffu + ((u>>16)&1u);
    return (ushort_t)(r>>16);
}
__device__ __forceinline__ float bf2f(ushort_t s){ return __uint_as_float(((unsigned)s)<<16); }

__device__ __forceinline__ f32x4 mfma16(short8 a, short8 b, f32x4 c){
    return __builtin_amdgcn_mfma_f32_16x16x32_bf16(a, b, c, 0, 0, 0);
}

// ---------------- prep: weight cvt (bf16) + scalar setup + apow table ----------------
__global__ void prep_k(const float* __restrict__ s0, const float* __restrict__ s1,
                       const float* __restrict__ s2, const float* __restrict__ s3,
                       const float* __restrict__ s4, const float* __restrict__ s5,
                       ushort_t* __restrict__ d0, ushort_t* __restrict__ d1,
                       ushort_t* __restrict__ d2, ushort_t* __restrict__ d3,
                       ushort_t* __restrict__ d4, ushort_t* __restrict__ d5,
                       const float* __restrict__ logA_seq, const float* __restrict__ logdt_seq,
                       const float* __restrict__ logA_dep, const float* __restrict__ logdt_dep,
                       const int* __restrict__ active_k,
                       float* __restrict__ aseq, float* __restrict__ apowC,
                       float* __restrict__ gain, float* __restrict__ apowtab){
    int i = blockIdx.x*256 + threadIdx.x;
    if      (i < 65536)   d0[i] = f2bf(s0[i]);
    else if (i < 131072)  d1[i-65536] = f2bf(s1[i-65536]);
    else if (i < 327680)  d2[i-131072] = f2bf(s2[i-131072]);
    else if (i < 393216)  d3[i-327680] = f2bf(s3[i-327680]);
    else if (i < 458752)  d4[i-393216] = f2bf(s4[i-393216]);
    else if (i < 524288)  d5[i-458752] = f2bf(s5[i-458752]);
    else if (i < 524288 + D_){
        int d = i - 524288;
        float K = (float)(*active_k);
        float a = expf(-expf(logA_seq[d]) * expf(logdt_seq[d]));
        a = fmaxf(a, 1e-6f);
        aseq[d] = a;
        apowC[d] = powf(a, (float)CHUNK_);
        // apowtab[s][d] = a^(s+1), s = row index within 64-chunk
        float ap = a;
        for (int s2=0;s2<CHUNK_;++s2){ apowtab[s2*D_ + d] = ap; ap *= a; }
        float g;
        if (d < 128) {
            g = K;
        } else {
            float ad = expf(-expf(logA_dep[d-128]) * expf(logdt_dep[d-128]));
            float om = 1.0f - ad;
            if (fabsf(om) < 1e-6f) g = K;
            else g = (1.0f - powf(ad, K)) / fmaxf(om, 1e-8f);
        }
        gain[d] = g;
    }
}

// ---------------- rms_norm(x) -> e bf16 (R7-proven form) ----------------
__global__ __launch_bounds__(256) void rmsbf_k(const float* __restrict__ x, ushort_t* __restrict__ e){
    int row = blockIdx.x;
    int tid = threadIdx.x;
    float4 v = ((const float4*)(x + (size_t)row*D_))[tid];
    float ss = v.x*v.x + v.y*v.y + v.z*v.z + v.w*v.w;
    for (int off=32; off; off>>=1) ss += __shfl_down(ss, off, 64);
    __shared__ float red[4];
    if ((tid&63)==0) red[tid>>6] = ss;
    __syncthreads();
    float tot = red[0]+red[1]+red[2]+red[3];
    float scale = 1.0f / sqrtf(tot*(1.0f/D_) + EPS_);
    ushort4 o;
    o.x = f2bf(v.x*scale); o.y = f2bf(v.y*scale); o.z = f2bf(v.z*scale); o.w = f2bf(v.w*scale);
    ((ushort4*)(e + (size_t)row*D_))[tid] = o;
}

// ---------------- bd2s: blockdiags + IN-REGISTER chunk scan ----------------
// MFMA C-layout: lane (q=lane>>4, m=lane&15) holds rows 4q+r (r=0..3) of column
// c*16+m. Scan h_s = a*h_{s-1} + d_s done per tile: 3-fma local quad scan ->
// 2-step Hillis-Steele over quads of affine maps (M=a^4, B=p3) via shfl ->
// 4-fma h-chain. Replaces the 64-step serial LDS RMW chain (~9K dependent cyc).
__global__ __launch_bounds__(256) void bd2s_k(const ushort_t* __restrict__ e,
        const ushort_t* __restrict__ wseq, const ushort_t* __restrict__ wdep,
        const float* __restrict__ gain, const float* __restrict__ aseq,
        ushort_t* __restrict__ hsum, float* __restrict__ carry){
    __shared__ __align__(16) ushort_t st[4][16][72];   // store staging only (write-once/read-once)
    int wave = threadIdx.x>>6, lane = threadIdx.x&63;
    int m = lane&15, quad = lane>>4;
    int orow = lane>>2, oq = lane&3;
    int n = blockIdx.y;
    int chunk0 = blockIdx.x*256 + wave*64;

    short8 bs[2][4], bd[2][4];
    #pragma unroll
    for (int s=0;s<2;++s)
        #pragma unroll
        for (int c=0;c<4;++c){
            bs[s][c] = *(const short8*)(wseq + n*4096 + (c*16+m)*64 + s*32 + quad*8);
            bd[s][c] = *(const short8*)(wdep + n*4096 + (c*16+m)*64 + s*32 + quad*8);
        }
    float g[4], av[4], a4v[4], C[4];
    #pragma unroll
    for (int c=0;c<4;++c){
        g[c]  = gain[n*64 + c*16 + m];
        float a = aseq[n*64 + c*16 + m];
        av[c] = a;
        float a2 = a*a;
        a4v[c] = a2*a2;
        C[c] = 0.f;
    }

    #pragma unroll
    for (int t=0;t<4;++t){
        int r0 = chunk0 + t*16;
        const ushort_t* ab = e + (size_t)(r0+m)*D_ + n*64 + quad*8;
        short8 a0 = *(const short8*)ab;
        short8 a1 = *(const short8*)(ab + 32);
        f32x4 accs[4], accd[4];
        #pragma unroll
        for (int c=0;c<4;++c){
            accs[c]=(f32x4)0.f; accd[c]=(f32x4)0.f;
            accs[c]=mfma16(a0, bs[0][c], accs[c]);
            accd[c]=mfma16(a0, bd[0][c], accd[c]);
            accs[c]=mfma16(a1, bs[1][c], accs[c]);
            accd[c]=mfma16(a1, bd[1][c], accd[c]);
        }
        #pragma unroll
        for (int c=0;c<4;++c){
            float a  = av[c];
            float d0 = silu_f(accs[c][0]);
            float d1 = silu_f(accs[c][1]);
            float d2 = silu_f(accs[c][2]);
            float d3 = silu_f(accs[c][3]);
            // local zero-init scan (only p3 needed for quad composition)
            float p1 = fmaf(a, d0, d1);
            float p2 = fmaf(a, p1, d2);
            float p3 = fmaf(a, p2, d3);
            // Hillis-Steele over 4 quads of affine maps f(x) = M*x + B
            float M = a4v[c], Bv = p3;
            float Mp = __shfl_up(M, 16, 64);
            float Bp = __shfl_up(Bv, 16, 64);
            if (quad >= 1){ Bv = fmaf(M, Bp, Bv); M *= Mp; }
            Mp = __shfl_up(M, 32, 64);
            Bp = __shfl_up(Bv, 32, 64);
            if (quad >= 2){ Bv = fmaf(M, Bp, Bv); M *= Mp; }
            // K_q = F_{q-1}(C); quad 0 seeds with C
            float KB = __shfl_up(Bv, 16, 64);
            float KM = __shfl_up(M, 16, 64);
            float K  = (quad==0) ? C[c] : fmaf(KM, C[c], KB);
            // h-chain (exact recurrence from K)
            float h0 = fmaf(a, K,  d0);
            float h1 = fmaf(a, h0, d1);
            float h2 = fmaf(a, h1, d2);
            float h3 = fmaf(a, h2, d3);
            // carry out of tile: F_3(C) at quad 3, broadcast per column
            float Cn = fmaf(M, C[c], Bv);
            C[c] = __shfl(Cn, 48 + m, 64);
            st[wave][quad*4+0][c*16+m] = f2bf(h0 + g[c]*silu_f(accd[c][0]));
            st[wave][quad*4+1][c*16+m] = f2bf(h1 + g[c]*silu_f(accd[c][1]));
            st[wave][quad*4+2][c*16+m] = f2bf(h2 + g[c]*silu_f(accd[c][2]));
            st[wave][quad*4+3][c*16+m] = f2bf(h3 + g[c]*silu_f(accd[c][3]));
        }
        ushort_t* db = hsum + (size_t)(r0+orow)*D_ + n*64;
        #pragma unroll
        for (int it=0;it<2;++it)
            *(short8*)(db + (it*4+oq)*8) = *(const short8*)&st[wave][orow][(it*4+oq)*8];
    }
    // lane = quad*16+m writes column lane; its column's carry is C[quad]
    float Cv = (quad==0) ? C[0] : (quad==1) ? C[1] : (quad==2) ? C[2] : C[3];
    carry[(size_t)(chunk0>>6)*D_ + n*64 + lane] = Cv;
}

// ---------------- scan2: serial prefix over chunk carries (register preload) ----------------
__global__ __launch_bounds__(64) void scan2_k(float* __restrict__ carry, const float* __restrict__ apowC){
    int tid = blockIdx.x*64 + threadIdx.x;       // B_*D_ threads
    int d = tid & (D_-1);
    int b = tid >> 10;
    float aC = apowC[d];
    float s[NCH_];
    #pragma unroll
    for (int c=0;c<NCH_;++c) s[c] = carry[(size_t)(b*NCH_+c)*D_ + d];
    float pref = 0.f;
    #pragma unroll
    for (int c=0;c<NCH_;++c){
        float cur = s[c];
        carry[(size_t)(b*NCH_+c)*D_ + d] = pref;
        pref = fmaf(aC, pref, cur);
    }
}

// ---------------- scan3s: hn = rmsnorm(hsum + P*a^(s+1)) in ONE pass ----------------
__global__ __launch_bounds__(256) void scan3s_k(const ushort_t* __restrict__ hsum,
                                                const float* __restrict__ aseq,
                                                const float* __restrict__ carry,
                                                const float* __restrict__ apowtab,
                                                ushort_t* __restrict__ hn){
    __shared__ float part[4][4];
    __shared__ float scl[8];
    int tid = threadIdx.x;
    int lane = tid & 63, wave = tid >> 6;
    int cg = tid & 127;        // col group (8 cols)
    int rp = tid >> 7;         // row parity (0/1)
    int d0 = cg*8;
    int row0 = blockIdx.x*8;   // 8 rows, all within one 64-chunk
    int bc = row0 >> 6;
    int s0 = row0 & 63;

    float a2[8], P[8], apow[8];
    #pragma unroll
    for (int j=0;j<8;++j){
        float aj = aseq[d0+j];
        a2[j] = aj*aj;
        P[j]  = carry[(size_t)bc*D_ + d0 + j];
        apow[j] = apowtab[(size_t)(s0 + rp)*D_ + d0 + j];   // a^(s+1) at first row
    }

    float hf[4][8];
    #pragma unroll
    for (int i=0;i<4;++i){
        int row = row0 + i*2 + rp;
        short8 v = *(const short8*)(hsum + (size_t)row*D_ + d0);
        float ss = 0.f;
        #pragma unroll
        for (int j=0;j<8;++j){
            float f = bf2f((ushort_t)v[j]) + P[j]*apow[j];
            hf[i][j] = f;
            ss += f*f;
            apow[j] *= a2[j];
        }
        for (int off=32; off; off>>=1) ss += __shfl_down(ss, off, 64);
        if (lane==0) part[wave][i] = ss;
    }
    __syncthreads();
    if (tid < 8){
        int r = tid;                 // row index within block
        int rr = r & 1, ii = r >> 1;
        float sum = part[rr*2][ii] + part[rr*2+1][ii];
        scl[r] = rsqrtf(sum*(1.0f/D_) + EPS_);
    }
    __syncthreads();
    #pragma unroll
    for (int i=0;i<4;++i){
        int rloc = i*2 + rp;
        float sc = scl[rloc];
        short8 o;
        #pragma unroll
        for (int j=0;j<8;++j) o[j] = (short)f2bf(hf[i][j]*sc);
        *(short8*)(hn + (size_t)(row0 + rloc)*D_ + d0) = o;
    }
}

// ---------------- post: r = silu(concat[hn,e,eshift] @ wpost^T) bf16 ----------------
// R7-proven form (44.5us): s-loop outermost, unroll 1, loop-local loads.
__global__ __launch_bounds__(256) void post_k(const ushort_t* __restrict__ hn,
                                              const ushort_t* __restrict__ e,
                                              const ushort_t* __restrict__ wpost, ushort_t* __restrict__ rout){
    __shared__ __align__(16) ushort_t st[4][16][72];
    int wave = threadIdx.x>>6, lane = threadIdx.x&63;
    int m = lane&15, quad = lane>>4;
    int orow = lane>>2, oq = lane&3;
    int n = blockIdx.y;
    int row0 = blockIdx.x*128 + wave*32 + m;

    f32x4 acc[2][4];
    #pragma unroll
    for (int t=0;t<2;++t)
        #pragma unroll
        for (int c=0;c<4;++c) acc[t][c]=(f32x4)0.f;

    #pragma unroll 1
    for (int s=0;s<6;++s){
        int g0 = n*192 + s*32;
        short8 bw[4];
        #pragma unroll
        for (int c=0;c<4;++c)
            bw[c] = *(const short8*)(wpost + n*(64*192) + (c*16+m)*192 + s*32 + quad*8);
        #pragma unroll
        for (int t=0;t<2;++t){
            int row = row0 + t*16;
            short8 af;
            if (g0 < 1024){
                af = *(const short8*)(hn + (size_t)row*D_ + g0 + quad*8);
            } else if (g0 < 2048){
                af = *(const short8*)(e + (size_t)row*D_ + (g0-1024) + quad*8);
            } else {
                if ((row & (T_-1)) == 0) af = short8{0,0,0,0,0,0,0,0};
                else af = *(const short8*)(e + (size_t)(row-1)*D_ + (g0-2048) + quad*8);
            }
            #pragma unroll
            for (int c=0;c<4;++c)
                acc[t][c] = mfma16(af, bw[c], acc[t][c]);
        }
    }
    #pragma unroll
    for (int t=0;t<2;++t){
        int r0 = blockIdx.x*128 + wave*32 + t*16;
        #pragma unroll
        for (int c=0;c<4;++c)
            #pragma unroll
            for (int r=0;r<4;++r)
                st[wave][quad*4+r][c*16+m] = f2bf(silu_f(acc[t][c][r]));
        ushort_t* db = rout + (size_t)(r0+orow)*D_ + n*64;
        #pragma unroll
        for (int it=0;it<2;++it)
            *(short8*)(db + (it*4+oq)*8) = *(const short8*)&st[wave][orow][(it*4+oq)*8];
    }
}

// ---------------- rlow = r @ lrB^T (K=1024 -> 64) bf16, split-K over 4 waves ----------------
__global__ __launch_bounds__(256) void rlow_k(const ushort_t* __restrict__ r, const ushort_t* __restrict__ lrB,
                                              ushort_t* __restrict__ rlow){
    __shared__ __align__(16) float sacc[4][16][68];
    int wave = threadIdx.x>>6, lane = threadIdx.x&63;
    int m = lane&15, quad = lane>>4;
    int r0 = blockIdx.x*16;
    f32x4 acc[4];
    #pragma unroll
    for (int c=0;c<4;++c) acc[c]=(f32x4)0.f;
    const ushort_t* ab = r + (size_t)(r0+m)*D_ + wave*256 + quad*8;
    #pragma unroll
    for (int s=0;s<8;++s){
        short8 a = *(const short8*)(ab + s*32);
        #pragma unroll
        for (int c=0;c<4;++c){
            short8 b = *(const short8*)(lrB + (c*16+m)*1024 + wave*256 + s*32 + quad*8);
            acc[c] = mfma16(a, b, acc[c]);
        }
    }
    #pragma unroll
    for (int c=0;c<4;++c)
        #pragma unroll
        for (int r2=0;r2<4;++r2)
            sacc[wave][quad*4+r2][c*16+m] = acc[c][r2];
    __syncthreads();
    int row  = threadIdx.x>>4;        // 0..15
    int col4 = (threadIdx.x&15)*4;    // 0..60 step 4
    float4 v0 = *(const float4*)&sacc[0][row][col4];
    float4 v1 = *(const float4*)&sacc[1][row][col4];
    float4 v2 = *(const float4*)&sacc[2][row][col4];
    float4 v3 = *(const float4*)&sacc[3][row][col4];
    ushort4 o;
    o.x = f2bf(v0.x+v1.x+v2.x+v3.x);
    o.y = f2bf(v0.y+v1.y+v2.y+v3.y);
    o.z = f2bf(v0.z+v1.z+v2.z+v3.z);
    o.w = f2bf(v0.w+v1.w+v2.w+v3.w);
    *(ushort4*)(rlow + (size_t)(r0+row)*64 + col4) = o;
}

// ---------------- out = x + r@wloc^T + rlow@lrA^T ----------------
__global__ __launch_bounds__(256) void out_k(const float* __restrict__ x, const ushort_t* __restrict__ r,
        const ushort_t* __restrict__ rlow, const ushort_t* __restrict__ wloc, const ushort_t* __restrict__ lrA,
        float* __restrict__ out){
    __shared__ __align__(16) float st[4][16][68];
    int wave = threadIdx.x>>6, lane = threadIdx.x&63;
    int m = lane&15, quad = lane>>4;
    int orow = lane>>2, oq = lane&3;
    int n = blockIdx.y;
    int r0 = blockIdx.x*64 + wave*16;

    short8 wl[2][4], la[4][2];
    #pragma unroll
    for (int c=0;c<4;++c)
        #pragma unroll
        for (int s=0;s<2;++s){
            wl[s][c] = *(const short8*)(wloc + n*4096 + (c*16+m)*64 + s*32 + quad*8);
            la[c][s] = *(const short8*)(lrA + (size_t)(n*64 + c*16 + m)*64 + s*32 + quad*8);
        }
    const float* xb = x + (size_t)(r0+orow)*D_ + n*64;
    float4 xv[4];
    #pragma unroll
    for (int it=0;it<4;++it) xv[it] = *(const float4*)(xb + (it*4+oq)*4);

    const ushort_t* lb = rlow + (size_t)(r0+m)*64 + quad*8;
    short8 al0 = *(const short8*)lb;
    short8 al1 = *(const short8*)(lb + 32);
    const ushort_t* ab = r + (size_t)(r0+m)*D_ + n*64 + quad*8;
    short8 ar0 = *(const short8*)ab;
    short8 ar1 = *(const short8*)(ab + 32);
    f32x4 acc[4];
    #pragma unroll
    for (int c=0;c<4;++c){
        acc[c]=(f32x4)0.f;
        acc[c]=mfma16(al0, la[c][0], acc[c]);
        acc[c]=mfma16(al1, la[c][1], acc[c]);
        acc[c]=mfma16(ar0, wl[0][c], acc[c]);
        acc[c]=mfma16(ar1, wl[1][c], acc[c]);
    }
    #pragma unroll
    for (int c=0;c<4;++c)
        #pragma unroll
        for (int r2=0;r2<4;++r2)
            st[wave][quad*4+r2][c*16+m] = acc[c][r2];
    float* ob = out + (size_t)(r0+orow)*D_ + n*64;
    #pragma unroll
    for (int it=0;it<4;++it){
        float4 v = *(const float4*)&st[wave][orow][(it*4+oq)*4];
        v.x += xv[it].x; v.y += xv[it].y; v.z += xv[it].z; v.w += xv[it].w;
        *(float4*)(ob + (it*4+oq)*4) = v;
    }
}

extern "C" void kernel_launch(void* const* d_in, const int* in_sizes, int n_in,
                              void* d_out, int out_size, void* d_ws, size_t ws_size,
                              hipStream_t stream) {
    const float* x         = (const float*)d_in[0];
    const int*   active_k  = (const int*)  d_in[1];
    const float* b_seq_w   = (const float*)d_in[2];
    const float* b_depth_w = (const float*)d_in[3];
    const float* w_post_w  = (const float*)d_in[4];
    const float* w_local_w = (const float*)d_in[5];
    const float* lr_A      = (const float*)d_in[6];
    const float* lr_B      = (const float*)d_in[7];
    const float* logA_seq  = (const float*)d_in[8];
    const float* logdt_seq = (const float*)d_in[9];
    const float* logA_dep  = (const float*)d_in[10];
    const float* logdt_dep = (const float*)d_in[11];

    float* ws      = (float*)d_ws;
    float* carry   = ws;                             // B_*NCH_*D_ = 262144
    float* aseq    = carry + (size_t)B_*NCH_*D_;
    float* apowC   = aseq + D_;
    float* gain    = apowC + D_;
    float* apowtab = gain + D_;                      // CHUNK_*D_ = 65536
    ushort_t* ub       = (ushort_t*)(apowtab + (size_t)CHUNK_*D_);
    ushort_t* e_bf     = ub;                         // R_*D_
    ushort_t* hsum_bf  = e_bf + (size_t)R_*D_;       // R_*D_ (scanned drive + hdep)
    ushort_t* hn_bf    = hsum_bf + (size_t)R_*D_;    // R_*D_ (normalized h)
    ushort_t* r_bf     = hn_bf + (size_t)R_*D_;      // R_*D_
    ushort_t* rlow_bf  = r_bf + (size_t)R_*D_;       // R_*64
    ushort_t* wseq_bf  = rlow_bf + (size_t)R_*64;    // 65536
    ushort_t* wdep_bf  = wseq_bf + 65536;
    ushort_t* wpost_bf = wdep_bf + 65536;            // 196608
    ushort_t* wloc_bf  = wpost_bf + 196608;
    ushort_t* lrA_bf   = wloc_bf + 65536;
    ushort_t* lrB_bf   = lrA_bf + 65536;

    prep_k<<<(524288 + D_ + 255)/256, 256, 0, stream>>>(
        b_seq_w, b_depth_w, w_post_w, w_local_w, lr_A, lr_B,
        wseq_bf, wdep_bf, wpost_bf, wloc_bf, lrA_bf, lrB_bf,
        logA_seq, logdt_seq, logA_dep, logdt_dep, active_k, aseq, apowC, gain, apowtab);

    rmsbf_k <<<R_, 256, 0, stream>>>(x, e_bf);
    bd2s_k  <<<dim3(R_/256, 16), 256, 0, stream>>>(e_bf, wseq_bf, wdep_bf, gain, aseq,
                                                   hsum_bf, carry);
    scan2_k <<<(B_*D_)/64, 64, 0, stream>>>(carry, apowC);
    scan3s_k<<<R_/8, 256, 0, stream>>>(hsum_bf, aseq, carry, apowtab, hn_bf);
    post_k  <<<dim3(R_/128, 16), 256, 0, stream>>>(hn_bf, e_bf, wpost_bf, r_bf);
    rlow_k  <<<R_/16, 256, 0, stream>>>(r_bf, lrB_bf, rlow_bf);
    out_k   <<<dim3(R_/64, 16), 256, 0, stream>>>(x, r_bf, rlow_bf, wloc_bf, lrA_bf, (float*)d_out);
}

// Round 13
// 271.312 us; speedup vs baseline: 1.1430x; 1.0299x over previous
//
#include <hip/hip_runtime.h>

#define B_ 4
#define T_ 4096
#define D_ 1024
#define R_ (B_*T_)
#define CHUNK_ 64
#define NCH_ (T_/CHUNK_)
#define EPS_ 1.1920929e-07f

typedef unsigned short ushort_t;
typedef __attribute__((ext_vector_type(8))) short short8;
typedef __attribute__((ext_vector_type(4))) float f32x4;

__device__ __forceinline__ float silu_f(float v){ return v / (1.0f + __expf(-v)); }

__device__ __forceinline__ ushort_t f2bf(float f){
    unsigned u = __float_as_uint(f);
    unsigned r = u + 0x7fffu + ((u>>16)&1u);
    return (ushort_t)(r>>16);
}
__device__ __forceinline__ float bf2f(ushort_t s){ return __uint_as_float(((unsigned)s)<<16); }

__device__ __forceinline__ f32x4 mfma16(short8 a, short8 b, f32x4 c){
    return __builtin_amdgcn_mfma_f32_16x16x32_bf16(a, b, c, 0, 0, 0);
}

// ---------------- prep: weight cvt (bf16) + scalar setup + apow table ----------------
__global__ void prep_k(const float* __restrict__ s0, const float* __restrict__ s1,
                       const float* __restrict__ s2, const float* __restrict__ s3,
                       const float* __restrict__ s4, const float* __restrict__ s5,
                       ushort_t* __restrict__ d0, ushort_t* __restrict__ d1,
                       ushort_t* __restrict__ d2, ushort_t* __restrict__ d3,
                       ushort_t* __restrict__ d4, ushort_t* __restrict__ d5,
                       const float* __restrict__ logA_seq, const float* __restrict__ logdt_seq,
                       const float* __restrict__ logA_dep, const float* __restrict__ logdt_dep,
                       const int* __restrict__ active_k,
                       float* __restrict__ aseq, float* __restrict__ apowC,
                       float* __restrict__ gain, float* __restrict__ apowtab){
    int i = blockIdx.x*256 + threadIdx.x;
    if      (i < 65536)   d0[i] = f2bf(s0[i]);
    else if (i < 131072)  d1[i-65536] = f2bf(s1[i-65536]);
    else if (i < 327680)  d2[i-131072] = f2bf(s2[i-131072]);
    else if (i < 393216)  d3[i-327680] = f2bf(s3[i-327680]);
    else if (i < 458752)  d4[i-393216] = f2bf(s4[i-393216]);
    else if (i < 524288)  d5[i-458752] = f2bf(s5[i-458752]);
    else if (i < 524288 + D_){
        int d = i - 524288;
        float K = (float)(*active_k);
        float a = expf(-expf(logA_seq[d]) * expf(logdt_seq[d]));
        a = fmaxf(a, 1e-6f);
        aseq[d] = a;
        apowC[d] = powf(a, (float)CHUNK_);
        // apowtab[s][d] = a^(s+1), s = row index within 64-chunk
        float ap = a;
        for (int s2=0;s2<CHUNK_;++s2){ apowtab[s2*D_ + d] = ap; ap *= a; }
        float g;
        if (d < 128) {
            g = K;
        } else {
            float ad = expf(-expf(logA_dep[d-128]) * expf(logdt_dep[d-128]));
            float om = 1.0f - ad;
            if (fabsf(om) < 1e-6f) g = K;
            else g = (1.0f - powf(ad, K)) / fmaxf(om, 1e-8f);
        }
        gain[d] = g;
    }
}

// ---------------- rms_norm(x) -> e bf16 (R7-proven form) ----------------
__global__ __launch_bounds__(256) void rmsbf_k(const float* __restrict__ x, ushort_t* __restrict__ e){
    int row = blockIdx.x;
    int tid = threadIdx.x;
    float4 v = ((const float4*)(x + (size_t)row*D_))[tid];
    float ss = v.x*v.x + v.y*v.y + v.z*v.z + v.w*v.w;
    for (int off=32; off; off>>=1) ss += __shfl_down(ss, off, 64);
    __shared__ float red[4];
    if ((tid&63)==0) red[tid>>6] = ss;
    __syncthreads();
    float tot = red[0]+red[1]+red[2]+red[3];
    float scale = 1.0f / sqrtf(tot*(1.0f/D_) + EPS_);
    ushort4 o;
    o.x = f2bf(v.x*scale); o.y = f2bf(v.y*scale); o.z = f2bf(v.z*scale); o.w = f2bf(v.w*scale);
    ((ushort4*)(e + (size_t)row*D_))[tid] = o;
}

// ---------------- bd2s: blockdiags + IN-REGISTER chunk scan (R12-proven) ----------------
__global__ __launch_bounds__(256) void bd2s_k(const ushort_t* __restrict__ e,
        const ushort_t* __restrict__ wseq, const ushort_t* __restrict__ wdep,
        const float* __restrict__ gain, const float* __restrict__ aseq,
        ushort_t* __restrict__ hsum, float* __restrict__ carry){
    __shared__ __align__(16) ushort_t st[4][16][72];   // store staging only
    int wave = threadIdx.x>>6, lane = threadIdx.x&63;
    int m = lane&15, quad = lane>>4;
    int orow = lane>>2, oq = lane&3;
    int n = blockIdx.y;
    int chunk0 = blockIdx.x*256 + wave*64;

    short8 bs[2][4], bd[2][4];
    #pragma unroll
    for (int s=0;s<2;++s)
        #pragma unroll
        for (int c=0;c<4;++c){
            bs[s][c] = *(const short8*)(wseq + n*4096 + (c*16+m)*64 + s*32 + quad*8);
            bd[s][c] = *(const short8*)(wdep + n*4096 + (c*16+m)*64 + s*32 + quad*8);
        }
    float g[4], av[4], a4v[4], C[4];
    #pragma unroll
    for (int c=0;c<4;++c){
        g[c]  = gain[n*64 + c*16 + m];
        float a = aseq[n*64 + c*16 + m];
        av[c] = a;
        float a2 = a*a;
        a4v[c] = a2*a2;
        C[c] = 0.f;
    }

    #pragma unroll
    for (int t=0;t<4;++t){
        int r0 = chunk0 + t*16;
        const ushort_t* ab = e + (size_t)(r0+m)*D_ + n*64 + quad*8;
        short8 a0 = *(const short8*)ab;
        short8 a1 = *(const short8*)(ab + 32);
        f32x4 accs[4], accd[4];
        #pragma unroll
        for (int c=0;c<4;++c){
            accs[c]=(f32x4)0.f; accd[c]=(f32x4)0.f;
            accs[c]=mfma16(a0, bs[0][c], accs[c]);
            accd[c]=mfma16(a0, bd[0][c], accd[c]);
            accs[c]=mfma16(a1, bs[1][c], accs[c]);
            accd[c]=mfma16(a1, bd[1][c], accd[c]);
        }
        #pragma unroll
        for (int c=0;c<4;++c){
            float a  = av[c];
            float d0 = silu_f(accs[c][0]);
            float d1 = silu_f(accs[c][1]);
            float d2 = silu_f(accs[c][2]);
            float d3 = silu_f(accs[c][3]);
            float p1 = fmaf(a, d0, d1);
            float p2 = fmaf(a, p1, d2);
            float p3 = fmaf(a, p2, d3);
            // Hillis-Steele over 4 quads of affine maps f(x) = M*x + B
            float M = a4v[c], Bv = p3;
            float Mp = __shfl_up(M, 16, 64);
            float Bp = __shfl_up(Bv, 16, 64);
            if (quad >= 1){ Bv = fmaf(M, Bp, Bv); M *= Mp; }
            Mp = __shfl_up(M, 32, 64);
            Bp = __shfl_up(Bv, 32, 64);
            if (quad >= 2){ Bv = fmaf(M, Bp, Bv); M *= Mp; }
            float KB = __shfl_up(Bv, 16, 64);
            float KM = __shfl_up(M, 16, 64);
            float K  = (quad==0) ? C[c] : fmaf(KM, C[c], KB);
            float h0 = fmaf(a, K,  d0);
            float h1 = fmaf(a, h0, d1);
            float h2 = fmaf(a, h1, d2);
            float h3 = fmaf(a, h2, d3);
            float Cn = fmaf(M, C[c], Bv);
            C[c] = __shfl(Cn, 48 + m, 64);
            st[wave][quad*4+0][c*16+m] = f2bf(h0 + g[c]*silu_f(accd[c][0]));
            st[wave][quad*4+1][c*16+m] = f2bf(h1 + g[c]*silu_f(accd[c][1]));
            st[wave][quad*4+2][c*16+m] = f2bf(h2 + g[c]*silu_f(accd[c][2]));
            st[wave][quad*4+3][c*16+m] = f2bf(h3 + g[c]*silu_f(accd[c][3]));
        }
        ushort_t* db = hsum + (size_t)(r0+orow)*D_ + n*64;
        #pragma unroll
        for (int it=0;it<2;++it)
            *(short8*)(db + (it*4+oq)*8) = *(const short8*)&st[wave][orow][(it*4+oq)*8];
    }
    float Cv = (quad==0) ? C[0] : (quad==1) ? C[1] : (quad==2) ? C[2] : C[3];
    carry[(size_t)(chunk0>>6)*D_ + n*64 + lane] = Cv;
}

// ---------------- scan2: serial prefix over chunk carries (register preload) ----------------
__global__ __launch_bounds__(64) void scan2_k(float* __restrict__ carry, const float* __restrict__ apowC){
    int tid = blockIdx.x*64 + threadIdx.x;       // B_*D_ threads
    int d = tid & (D_-1);
    int b = tid >> 10;
    float aC = apowC[d];
    float s[NCH_];
    #pragma unroll
    for (int c=0;c<NCH_;++c) s[c] = carry[(size_t)(b*NCH_+c)*D_ + d];
    float pref = 0.f;
    #pragma unroll
    for (int c=0;c<NCH_;++c){
        float cur = s[c];
        carry[(size_t)(b*NCH_+c)*D_ + d] = pref;
        pref = fmaf(aC, pref, cur);
    }
}

// ---------------- scan3s: hn = rmsnorm(hsum + P*a^(s+1)) in ONE pass ----------------
__global__ __launch_bounds__(256) void scan3s_k(const ushort_t* __restrict__ hsum,
                                                const float* __restrict__ aseq,
                                                const float* __restrict__ carry,
                                                const float* __restrict__ apowtab,
                                                ushort_t* __restrict__ hn){
    __shared__ float part[4][4];
    __shared__ float scl[8];
    int tid = threadIdx.x;
    int lane = tid & 63, wave = tid >> 6;
    int cg = tid & 127;        // col group (8 cols)
    int rp = tid >> 7;         // row parity (0/1)
    int d0 = cg*8;
    int row0 = blockIdx.x*8;   // 8 rows, all within one 64-chunk
    int bc = row0 >> 6;
    int s0 = row0 & 63;

    float a2[8], P[8], apow[8];
    #pragma unroll
    for (int j=0;j<8;++j){
        float aj = aseq[d0+j];
        a2[j] = aj*aj;
        P[j]  = carry[(size_t)bc*D_ + d0 + j];
        apow[j] = apowtab[(size_t)(s0 + rp)*D_ + d0 + j];   // a^(s+1) at first row
    }

    float hf[4][8];
    #pragma unroll
    for (int i=0;i<4;++i){
        int row = row0 + i*2 + rp;
        short8 v = *(const short8*)(hsum + (size_t)row*D_ + d0);
        float ss = 0.f;
        #pragma unroll
        for (int j=0;j<8;++j){
            float f = bf2f((ushort_t)v[j]) + P[j]*apow[j];
            hf[i][j] = f;
            ss += f*f;
            apow[j] *= a2[j];
        }
        for (int off=32; off; off>>=1) ss += __shfl_down(ss, off, 64);
        if (lane==0) part[wave][i] = ss;
    }
    __syncthreads();
    if (tid < 8){
        int r = tid;                 // row index within block
        int rr = r & 1, ii = r >> 1;
        float sum = part[rr*2][ii] + part[rr*2+1][ii];
        scl[r] = rsqrtf(sum*(1.0f/D_) + EPS_);
    }
    __syncthreads();
    #pragma unroll
    for (int i=0;i<4;++i){
        int rloc = i*2 + rp;
        float sc = scl[rloc];
        short8 o;
        #pragma unroll
        for (int j=0;j<8;++j) o[j] = (short)f2bf(hf[i][j]*sc);
        *(short8*)(hn + (size_t)(row0 + rloc)*D_ + d0) = o;
    }
}

// ---------------- post: r = silu(concat[hn,e,eshift] @ wpost^T) bf16 ----------------
// R7-proven form (44.5us): s-loop outermost, unroll 1, loop-local loads.
__global__ __launch_bounds__(256) void post_k(const ushort_t* __restrict__ hn,
                                              const ushort_t* __restrict__ e,
                                              const ushort_t* __restrict__ wpost, ushort_t* __restrict__ rout){
    __shared__ __align__(16) ushort_t st[4][16][72];
    int wave = threadIdx.x>>6, lane = threadIdx.x&63;
    int m = lane&15, quad = lane>>4;
    int orow = lane>>2, oq = lane&3;
    int n = blockIdx.y;
    int row0 = blockIdx.x*128 + wave*32 + m;

    f32x4 acc[2][4];
    #pragma unroll
    for (int t=0;t<2;++t)
        #pragma unroll
        for (int c=0;c<4;++c) acc[t][c]=(f32x4)0.f;

    #pragma unroll 1
    for (int s=0;s<6;++s){
        int g0 = n*192 + s*32;
        short8 bw[4];
        #pragma unroll
        for (int c=0;c<4;++c)
            bw[c] = *(const short8*)(wpost + n*(64*192) + (c*16+m)*192 + s*32 + quad*8);
        #pragma unroll
        for (int t=0;t<2;++t){
            int row = row0 + t*16;
            short8 af;
            if (g0 < 1024){
                af = *(const short8*)(hn + (size_t)row*D_ + g0 + quad*8);
            } else if (g0 < 2048){
                af = *(const short8*)(e + (size_t)row*D_ + (g0-1024) + quad*8);
            } else {
                if ((row & (T_-1)) == 0) af = short8{0,0,0,0,0,0,0,0};
                else af = *(const short8*)(e + (size_t)(row-1)*D_ + (g0-2048) + quad*8);
            }
            #pragma unroll
            for (int c=0;c<4;++c)
                acc[t][c] = mfma16(af, bw[c], acc[t][c]);
        }
    }
    #pragma unroll
    for (int t=0;t<2;++t){
        int r0 = blockIdx.x*128 + wave*32 + t*16;
        #pragma unroll
        for (int c=0;c<4;++c)
            #pragma unroll
            for (int r=0;r<4;++r)
                st[wave][quad*4+r][c*16+m] = f2bf(silu_f(acc[t][c][r]));
        ushort_t* db = rout + (size_t)(r0+orow)*D_ + n*64;
        #pragma unroll
        for (int it=0;it<2;++it)
            *(short8*)(db + (it*4+oq)*8) = *(const short8*)&st[wave][orow][(it*4+oq)*8];
    }
}

// ---------------- rlow = r @ lrB^T (K=1024 -> 64) bf16, split-K over 4 waves ----------------
__global__ __launch_bounds__(256) void rlow_k(const ushort_t* __restrict__ r, const ushort_t* __restrict__ lrB,
                                              ushort_t* __restrict__ rlow){
    __shared__ __align__(16) float sacc[4][16][68];
    int wave = threadIdx.x>>6, lane = threadIdx.x&63;
    int m = lane&15, quad = lane>>4;
    int r0 = blockIdx.x*16;
    f32x4 acc[4];
    #pragma unroll
    for (int c=0;c<4;++c) acc[c]=(f32x4)0.f;
    const ushort_t* ab = r + (size_t)(r0+m)*D_ + wave*256 + quad*8;
    #pragma unroll
    for (int s=0;s<8;++s){
        short8 a = *(const short8*)(ab + s*32);
        #pragma unroll
        for (int c=0;c<4;++c){
            short8 b = *(const short8*)(lrB + (c*16+m)*1024 + wave*256 + s*32 + quad*8);
            acc[c] = mfma16(a, b, acc[c]);
        }
    }
    #pragma unroll
    for (int c=0;c<4;++c)
        #pragma unroll
        for (int r2=0;r2<4;++r2)
            sacc[wave][quad*4+r2][c*16+m] = acc[c][r2];
    __syncthreads();
    int row  = threadIdx.x>>4;        // 0..15
    int col4 = (threadIdx.x&15)*4;    // 0..60 step 4
    float4 v0 = *(const float4*)&sacc[0][row][col4];
    float4 v1 = *(const float4*)&sacc[1][row][col4];
    float4 v2 = *(const float4*)&sacc[2][row][col4];
    float4 v3 = *(const float4*)&sacc[3][row][col4];
    ushort4 o;
    o.x = f2bf(v0.x+v1.x+v2.x+v3.x);
    o.y = f2bf(v0.y+v1.y+v2.y+v3.y);
    o.z = f2bf(v0.z+v1.z+v2.z+v3.z);
    o.w = f2bf(v0.w+v1.w+v2.w+v3.w);
    *(ushort4*)(rlow + (size_t)(r0+row)*64 + col4) = o;
}

// ---------------- out = x + r@wloc^T + rlow@lrA^T (R7-proven form) ----------------
__global__ __launch_bounds__(256) void out_k(const float* __restrict__ x, const ushort_t* __restrict__ r,
        const ushort_t* __restrict__ rlow, const ushort_t* __restrict__ wloc, const ushort_t* __restrict__ lrA,
        float* __restrict__ out){
    __shared__ __align__(16) float st[4][16][68];
    int wave = threadIdx.x>>6, lane = threadIdx.x&63;
    int m = lane&15, quad = lane>>4;
    int orow = lane>>2, oq = lane&3;
    int n = blockIdx.y;

    short8 wl[2][4], la[4][2];
    #pragma unroll
    for (int c=0;c<4;++c)
        #pragma unroll
        for (int s=0;s<2;++s){
            wl[s][c] = *(const short8*)(wloc + n*4096 + (c*16+m)*64 + s*32 + quad*8);
            la[c][s] = *(const short8*)(lrA + (size_t)(n*64 + c*16 + m)*64 + s*32 + quad*8);
        }
    #pragma unroll
    for (int t=0;t<2;++t){
        int r0 = blockIdx.x*128 + wave*32 + t*16;
        const float* xb = x + (size_t)(r0+orow)*D_ + n*64;
        float4 xv[4];
        #pragma unroll
        for (int it=0;it<4;++it) xv[it] = *(const float4*)(xb + (it*4+oq)*4);

        const ushort_t* lb = rlow + (size_t)(r0+m)*64 + quad*8;
        short8 al0 = *(const short8*)lb;
        short8 al1 = *(const short8*)(lb + 32);
        const ushort_t* ab = r + (size_t)(r0+m)*D_ + n*64 + quad*8;
        short8 ar0 = *(const short8*)ab;
        short8 ar1 = *(const short8*)(ab + 32);
        f32x4 acc[4];
        #pragma unroll
        for (int c=0;c<4;++c){
            acc[c]=(f32x4)0.f;
            acc[c]=mfma16(al0, la[c][0], acc[c]);
            acc[c]=mfma16(al1, la[c][1], acc[c]);
            acc[c]=mfma16(ar0, wl[0][c], acc[c]);
            acc[c]=mfma16(ar1, wl[1][c], acc[c]);
        }
        #pragma unroll
        for (int c=0;c<4;++c)
            #pragma unroll
            for (int r2=0;r2<4;++r2)
                st[wave][quad*4+r2][c*16+m] = acc[c][r2];
        float* ob = out + (size_t)(r0+orow)*D_ + n*64;
        #pragma unroll
        for (int it=0;it<4;++it){
            float4 v = *(const float4*)&st[wave][orow][(it*4+oq)*4];
            v.x += xv[it].x; v.y += xv[it].y; v.z += xv[it].z; v.w += xv[it].w;
            *(float4*)(ob + (it*4+oq)*4) = v;
        }
    }
}

extern "C" void kernel_launch(void* const* d_in, const int* in_sizes, int n_in,
                              void* d_out, int out_size, void* d_ws, size_t ws_size,
                              hipStream_t stream) {
    const float* x         = (const float*)d_in[0];
    const int*   active_k  = (const int*)  d_in[1];
    const float* b_seq_w   = (const float*)d_in[2];
    const float* b_depth_w = (const float*)d_in[3];
    const float* w_post_w  = (const float*)d_in[4];
    const float* w_local_w = (const float*)d_in[5];
    const float* lr_A      = (const float*)d_in[6];
    const float* lr_B      = (const float*)d_in[7];
    const float* logA_seq  = (const float*)d_in[8];
    const float* logdt_seq = (const float*)d_in[9];
    const float* logA_dep  = (const float*)d_in[10];
    const float* logdt_dep = (const float*)d_in[11];

    float* ws      = (float*)d_ws;
    float* carry   = ws;                             // B_*NCH_*D_ = 262144
    float* aseq    = carry + (size_t)B_*NCH_*D_;
    float* apowC   = aseq + D_;
    float* gain    = apowC + D_;
    float* apowtab = gain + D_;                      // CHUNK_*D_ = 65536
    ushort_t* ub       = (ushort_t*)(apowtab + (size_t)CHUNK_*D_);
    ushort_t* e_bf     = ub;                         // R_*D_
    ushort_t* hsum_bf  = e_bf + (size_t)R_*D_;       // R_*D_ (scanned drive + hdep)
    ushort_t* hn_bf    = hsum_bf + (size_t)R_*D_;    // R_*D_ (normalized h)
    ushort_t* r_bf     = hn_bf + (size_t)R_*D_;      // R_*D_
    ushort_t* rlow_bf  = r_bf + (size_t)R_*D_;       // R_*64
    ushort_t* wseq_bf  = rlow_bf + (size_t)R_*64;    // 65536
    ushort_t* wdep_bf  = wseq_bf + 65536;
    ushort_t* wpost_bf = wdep_bf + 65536;            // 196608
    ushort_t* wloc_bf  = wpost_bf + 196608;
    ushort_t* lrA_bf   = wloc_bf + 65536;
    ushort_t* lrB_bf   = lrA_bf + 65536;

    prep_k<<<(524288 + D_ + 255)/256, 256, 0, stream>>>(
        b_seq_w, b_depth_w, w_post_w, w_local_w, lr_A, lr_B,
        wseq_bf, wdep_bf, wpost_bf, wloc_bf, lrA_bf, lrB_bf,
        logA_seq, logdt_seq, logA_dep, logdt_dep, active_k, aseq, apowC, gain, apowtab);

    rmsbf_k <<<R_, 256, 0, stream>>>(x, e_bf);
    bd2s_k  <<<dim3(R_/256, 16), 256, 0, stream>>>(e_bf, wseq_bf, wdep_bf, gain, aseq,
                                                   hsum_bf, carry);
    scan2_k <<<(B_*D_)/64, 64, 0, stream>>>(carry, apowC);
    scan3s_k<<<R_/8, 256, 0, stream>>>(hsum_bf, aseq, carry, apowtab, hn_bf);
    post_k  <<<dim3(R_/128, 16), 256, 0, stream>>>(hn_bf, e_bf, wpost_bf, r_bf);
    rlow_k  <<<R_/16, 256, 0, stream>>>(r_bf, lrB_bf, rlow_bf);
    out_k   <<<dim3(R_/128, 16), 256, 0, stream>>>(x, r_bf, rlow_bf, wloc_bf, lrA_bf, (float*)d_out);
}

// Round 14
// 258.948 us; speedup vs baseline: 1.1976x; 1.0477x over previous
//
#include <hip/hip_runtime.h>

#define B_ 4
#define T_ 4096
#define D_ 1024
#define R_ (B_*T_)
#define CHUNK_ 64
#define NCH_ (T_/CHUNK_)
#define EPS_ 1.1920929e-07f

typedef unsigned short ushort_t;
typedef __attribute__((ext_vector_type(8))) short short8;
typedef __attribute__((ext_vector_type(4))) float f32x4;
typedef __attribute__((address_space(1))) ushort_t gu16;
typedef __attribute__((address_space(3))) ushort_t lu16;

__device__ __forceinline__ float silu_f(float v){ return v / (1.0f + __expf(-v)); }

__device__ __forceinline__ ushort_t f2bf(float f){
    unsigned u = __float_as_uint(f);
    unsigned r = u + 0x7fffu + ((u>>16)&1u);
    return (ushort_t)(r>>16);
}
__device__ __forceinline__ float bf2f(ushort_t s){ return __uint_as_float(((unsigned)s)<<16); }

__device__ __forceinline__ f32x4 mfma16(short8 a, short8 b, f32x4 c){
    return __builtin_amdgcn_mfma_f32_16x16x32_bf16(a, b, c, 0, 0, 0);
}

// ---------------- prep: weight cvt (bf16) + scalar setup + apow table ----------------
__global__ void prep_k(const float* __restrict__ s0, const float* __restrict__ s1,
                       const float* __restrict__ s2, const float* __restrict__ s3,
                       const float* __restrict__ s4, const float* __restrict__ s5,
                       ushort_t* __restrict__ d0, ushort_t* __restrict__ d1,
                       ushort_t* __restrict__ d2, ushort_t* __restrict__ d3,
                       ushort_t* __restrict__ d4, ushort_t* __restrict__ d5,
                       const float* __restrict__ logA_seq, const float* __restrict__ logdt_seq,
                       const float* __restrict__ logA_dep, const float* __restrict__ logdt_dep,
                       const int* __restrict__ active_k,
                       float* __restrict__ aseq, float* __restrict__ apowC,
                       float* __restrict__ gain, float* __restrict__ apowtab){
    int i = blockIdx.x*256 + threadIdx.x;
    if      (i < 65536)   d0[i] = f2bf(s0[i]);
    else if (i < 131072)  d1[i-65536] = f2bf(s1[i-65536]);
    else if (i < 327680)  d2[i-131072] = f2bf(s2[i-131072]);
    else if (i < 393216)  d3[i-327680] = f2bf(s3[i-327680]);
    else if (i < 458752)  d4[i-393216] = f2bf(s4[i-393216]);
    else if (i < 524288)  d5[i-458752] = f2bf(s5[i-458752]);
    else if (i < 524288 + D_){
        int d = i - 524288;
        float K = (float)(*active_k);
        float a = expf(-expf(logA_seq[d]) * expf(logdt_seq[d]));
        a = fmaxf(a, 1e-6f);
        aseq[d] = a;
        apowC[d] = powf(a, (float)CHUNK_);
        // apowtab[s][d] = a^(s+1), s = row index within 64-chunk
        float ap = a;
        for (int s2=0;s2<CHUNK_;++s2){ apowtab[s2*D_ + d] = ap; ap *= a; }
        float g;
        if (d < 128) {
            g = K;
        } else {
            float ad = expf(-expf(logA_dep[d-128]) * expf(logdt_dep[d-128]));
            float om = 1.0f - ad;
            if (fabsf(om) < 1e-6f) g = K;
            else g = (1.0f - powf(ad, K)) / fmaxf(om, 1e-8f);
        }
        gain[d] = g;
    }
}

// ---------------- rms_norm(x) -> e bf16 (R7-proven form) ----------------
__global__ __launch_bounds__(256) void rmsbf_k(const float* __restrict__ x, ushort_t* __restrict__ e){
    int row = blockIdx.x;
    int tid = threadIdx.x;
    float4 v = ((const float4*)(x + (size_t)row*D_))[tid];
    float ss = v.x*v.x + v.y*v.y + v.z*v.z + v.w*v.w;
    for (int off=32; off; off>>=1) ss += __shfl_down(ss, off, 64);
    __shared__ float red[4];
    if ((tid&63)==0) red[tid>>6] = ss;
    __syncthreads();
    float tot = red[0]+red[1]+red[2]+red[3];
    float scale = 1.0f / sqrtf(tot*(1.0f/D_) + EPS_);
    ushort4 o;
    o.x = f2bf(v.x*scale); o.y = f2bf(v.y*scale); o.z = f2bf(v.z*scale); o.w = f2bf(v.w*scale);
    ((ushort4*)(e + (size_t)row*D_))[tid] = o;
}

// ---------------- bd2s: blockdiags + IN-REGISTER chunk scan (R12-proven) ----------------
__global__ __launch_bounds__(256) void bd2s_k(const ushort_t* __restrict__ e,
        const ushort_t* __restrict__ wseq, const ushort_t* __restrict__ wdep,
        const float* __restrict__ gain, const float* __restrict__ aseq,
        ushort_t* __restrict__ hsum, float* __restrict__ carry){
    __shared__ __align__(16) ushort_t st[4][16][72];   // store staging only
    int wave = threadIdx.x>>6, lane = threadIdx.x&63;
    int m = lane&15, quad = lane>>4;
    int orow = lane>>2, oq = lane&3;
    int n = blockIdx.y;
    int chunk0 = blockIdx.x*256 + wave*64;

    short8 bs[2][4], bd[2][4];
    #pragma unroll
    for (int s=0;s<2;++s)
        #pragma unroll
        for (int c=0;c<4;++c){
            bs[s][c] = *(const short8*)(wseq + n*4096 + (c*16+m)*64 + s*32 + quad*8);
            bd[s][c] = *(const short8*)(wdep + n*4096 + (c*16+m)*64 + s*32 + quad*8);
        }
    float g[4], av[4], a4v[4], C[4];
    #pragma unroll
    for (int c=0;c<4;++c){
        g[c]  = gain[n*64 + c*16 + m];
        float a = aseq[n*64 + c*16 + m];
        av[c] = a;
        float a2 = a*a;
        a4v[c] = a2*a2;
        C[c] = 0.f;
    }

    #pragma unroll
    for (int t=0;t<4;++t){
        int r0 = chunk0 + t*16;
        const ushort_t* ab = e + (size_t)(r0+m)*D_ + n*64 + quad*8;
        short8 a0 = *(const short8*)ab;
        short8 a1 = *(const short8*)(ab + 32);
        f32x4 accs[4], accd[4];
        #pragma unroll
        for (int c=0;c<4;++c){
            accs[c]=(f32x4)0.f; accd[c]=(f32x4)0.f;
            accs[c]=mfma16(a0, bs[0][c], accs[c]);
            accd[c]=mfma16(a0, bd[0][c], accd[c]);
            accs[c]=mfma16(a1, bs[1][c], accs[c]);
            accd[c]=mfma16(a1, bd[1][c], accd[c]);
        }
        #pragma unroll
        for (int c=0;c<4;++c){
            float a  = av[c];
            float d0 = silu_f(accs[c][0]);
            float d1 = silu_f(accs[c][1]);
            float d2 = silu_f(accs[c][2]);
            float d3 = silu_f(accs[c][3]);
            float p1 = fmaf(a, d0, d1);
            float p2 = fmaf(a, p1, d2);
            float p3 = fmaf(a, p2, d3);
            // Hillis-Steele over 4 quads of affine maps f(x) = M*x + B
            float M = a4v[c], Bv = p3;
            float Mp = __shfl_up(M, 16, 64);
            float Bp = __shfl_up(Bv, 16, 64);
            if (quad >= 1){ Bv = fmaf(M, Bp, Bv); M *= Mp; }
            Mp = __shfl_up(M, 32, 64);
            Bp = __shfl_up(Bv, 32, 64);
            if (quad >= 2){ Bv = fmaf(M, Bp, Bv); M *= Mp; }
            float KB = __shfl_up(Bv, 16, 64);
            float KM = __shfl_up(M, 16, 64);
            float K  = (quad==0) ? C[c] : fmaf(KM, C[c], KB);
            float h0 = fmaf(a, K,  d0);
            float h1 = fmaf(a, h0, d1);
            float h2 = fmaf(a, h1, d2);
            float h3 = fmaf(a, h2, d3);
            float Cn = fmaf(M, C[c], Bv);
            C[c] = __shfl(Cn, 48 + m, 64);
            st[wave][quad*4+0][c*16+m] = f2bf(h0 + g[c]*silu_f(accd[c][0]));
            st[wave][quad*4+1][c*16+m] = f2bf(h1 + g[c]*silu_f(accd[c][1]));
            st[wave][quad*4+2][c*16+m] = f2bf(h2 + g[c]*silu_f(accd[c][2]));
            st[wave][quad*4+3][c*16+m] = f2bf(h3 + g[c]*silu_f(accd[c][3]));
        }
        ushort_t* db = hsum + (size_t)(r0+orow)*D_ + n*64;
        #pragma unroll
        for (int it=0;it<2;++it)
            *(short8*)(db + (it*4+oq)*8) = *(const short8*)&st[wave][orow][(it*4+oq)*8];
    }
    float Cv = (quad==0) ? C[0] : (quad==1) ? C[1] : (quad==2) ? C[2] : C[3];
    carry[(size_t)(chunk0>>6)*D_ + n*64 + lane] = Cv;
}

// ---------------- scan2: serial prefix over chunk carries (register preload) ----------------
__global__ __launch_bounds__(64) void scan2_k(float* __restrict__ carry, const float* __restrict__ apowC){
    int tid = blockIdx.x*64 + threadIdx.x;       // B_*D_ threads
    int d = tid & (D_-1);
    int b = tid >> 10;
    float aC = apowC[d];
    float s[NCH_];
    #pragma unroll
    for (int c=0;c<NCH_;++c) s[c] = carry[(size_t)(b*NCH_+c)*D_ + d];
    float pref = 0.f;
    #pragma unroll
    for (int c=0;c<NCH_;++c){
        float cur = s[c];
        carry[(size_t)(b*NCH_+c)*D_ + d] = pref;
        pref = fmaf(aC, pref, cur);
    }
}

// ---------------- scan3s: hn = rmsnorm(hsum + P*a^(s+1)) in ONE pass ----------------
__global__ __launch_bounds__(256) void scan3s_k(const ushort_t* __restrict__ hsum,
                                                const float* __restrict__ aseq,
                                                const float* __restrict__ carry,
                                                const float* __restrict__ apowtab,
                                                ushort_t* __restrict__ hn){
    __shared__ float part[4][4];
    __shared__ float scl[8];
    int tid = threadIdx.x;
    int lane = tid & 63, wave = tid >> 6;
    int cg = tid & 127;        // col group (8 cols)
    int rp = tid >> 7;         // row parity (0/1)
    int d0 = cg*8;
    int row0 = blockIdx.x*8;   // 8 rows, all within one 64-chunk
    int bc = row0 >> 6;
    int s0 = row0 & 63;

    float a2[8], P[8], apow[8];
    #pragma unroll
    for (int j=0;j<8;++j){
        float aj = aseq[d0+j];
        a2[j] = aj*aj;
        P[j]  = carry[(size_t)bc*D_ + d0 + j];
        apow[j] = apowtab[(size_t)(s0 + rp)*D_ + d0 + j];   // a^(s+1) at first row
    }

    float hf[4][8];
    #pragma unroll
    for (int i=0;i<4;++i){
        int row = row0 + i*2 + rp;
        short8 v = *(const short8*)(hsum + (size_t)row*D_ + d0);
        float ss = 0.f;
        #pragma unroll
        for (int j=0;j<8;++j){
            float f = bf2f((ushort_t)v[j]) + P[j]*apow[j];
            hf[i][j] = f;
            ss += f*f;
            apow[j] *= a2[j];
        }
        for (int off=32; off; off>>=1) ss += __shfl_down(ss, off, 64);
        if (lane==0) part[wave][i] = ss;
    }
    __syncthreads();
    if (tid < 8){
        int r = tid;                 // row index within block
        int rr = r & 1, ii = r >> 1;
        float sum = part[rr*2][ii] + part[rr*2+1][ii];
        scl[r] = rsqrtf(sum*(1.0f/D_) + EPS_);
    }
    __syncthreads();
    #pragma unroll
    for (int i=0;i<4;++i){
        int rloc = i*2 + rp;
        float sc = scl[rloc];
        short8 o;
        #pragma unroll
        for (int j=0;j<8;++j) o[j] = (short)f2bf(hf[i][j]*sc);
        *(short8*)(hn + (size_t)(row0 + rloc)*D_ + d0) = o;
    }
}

// ---------------- post: r = silu(concat[hn,e,eshift] @ wpost^T) bf16 ----------------
// Async-DMA experiment: wpost n-slice staged to LDS (so its VMEM ops retire
// before the DMAs -- vmcnt retires in order), then 12 activation tiles issued
// as global_load_lds (deep queue, zero VGPR cost), consumed with counted
// vmcnt(10..0) + sched_barrier. Out staging reuses the dead DMA region.
__global__ __launch_bounds__(256) void post_k(const ushort_t* __restrict__ hn,
                                              const ushort_t* __restrict__ e,
                                              const ushort_t* __restrict__ wpost, ushort_t* __restrict__ rout){
    __shared__ __align__(16) ushort_t stage[4][6144];   // 48KB: 12 x 1KB DMA tiles per wave
    __shared__ __align__(16) ushort_t wlds[64*208];     // 26.6KB padded weight slice (208: 16B-mult, 4-way banks)
    int wave = threadIdx.x>>6, lane = threadIdx.x&63;
    int m = lane&15, quad = lane>>4;
    int orow = lane>>2, oq = lane&3;
    int n = blockIdx.y;
    int row0 = blockIdx.x*128 + wave*32 + m;
    ushort_t* wst = &stage[wave][0];

    // cooperative weight stage: 64 rows x 192 ushorts -> padded 208 stride
    {
        const ushort_t* wsrc = wpost + n*(64*192);
        int tid = threadIdx.x;
        #pragma unroll
        for (int k=0;k<6;++k){
            int chunk = tid + k*256;            // 1536 chunks of 8 ushorts
            int rr = chunk / 24, cc = chunk % 24;
            *(short8*)(wlds + rr*208 + cc*8) = *(const short8*)(wsrc + rr*192 + cc*8);
        }
    }
    __syncthreads();   // drains weight loads; DMA queue starts empty

    // issue all 12 activation tile DMAs (idx = s*2+t, in order)
    #pragma unroll
    for (int s=0;s<6;++s){
        int g0 = n*192 + s*32;
        #pragma unroll
        for (int t=0;t<2;++t){
            int row = row0 + t*16;
            const ushort_t* src;
            if (g0 < 1024)      src = hn + (size_t)row*D_ + g0 + quad*8;
            else if (g0 < 2048) src = e + (size_t)row*D_ + (g0-1024) + quad*8;
            else                src = e + (size_t)(row-1)*D_ + (g0-2048) + quad*8;
            __builtin_amdgcn_global_load_lds((const gu16*)src, (lu16*)(wst + (s*2+t)*512), 16, 0, 0);
        }
    }

    f32x4 acc[2][4];
    #pragma unroll
    for (int t=0;t<2;++t)
        #pragma unroll
        for (int c=0;c<4;++c) acc[t][c]=(f32x4)0.f;

    #pragma unroll
    for (int s=0;s<6;++s){
        // wait for this s's two tiles (the 2 oldest outstanding DMAs)
        if      (s==0) asm volatile("s_waitcnt vmcnt(10)" ::: "memory");
        else if (s==1) asm volatile("s_waitcnt vmcnt(8)"  ::: "memory");
        else if (s==2) asm volatile("s_waitcnt vmcnt(6)"  ::: "memory");
        else if (s==3) asm volatile("s_waitcnt vmcnt(4)"  ::: "memory");
        else if (s==4) asm volatile("s_waitcnt vmcnt(2)"  ::: "memory");
        else           asm volatile("s_waitcnt vmcnt(0)"  ::: "memory");
        __builtin_amdgcn_sched_barrier(0);
        int g0 = n*192 + s*32;
        short8 bw[4];
        #pragma unroll
        for (int c=0;c<4;++c)
            bw[c] = *(const short8*)(wlds + (c*16+m)*208 + s*32 + quad*8);
        #pragma unroll
        for (int t=0;t<2;++t){
            short8 af = *(const short8*)(wst + (s*2+t)*512 + lane*8);
            int row = row0 + t*16;
            if (g0 >= 2048 && ((row & (T_-1)) == 0)) af = short8{0,0,0,0,0,0,0,0};
            #pragma unroll
            for (int c=0;c<4;++c)
                acc[t][c] = mfma16(af, bw[c], acc[t][c]);
        }
    }
    // out staging reuses the dead DMA region (wave-private, in-wave ds order)
    #pragma unroll
    for (int t=0;t<2;++t){
        int r0 = blockIdx.x*128 + wave*32 + t*16;
        #pragma unroll
        for (int c=0;c<4;++c)
            #pragma unroll
            for (int r=0;r<4;++r)
                wst[(quad*4+r)*72 + c*16+m] = f2bf(silu_f(acc[t][c][r]));
        ushort_t* db = rout + (size_t)(r0+orow)*D_ + n*64;
        #pragma unroll
        for (int it=0;it<2;++it)
            *(short8*)(db + (it*4+oq)*8) = *(const short8*)&wst[orow*72 + (it*4+oq)*8];
    }
}

// ---------------- rlow = r @ lrB^T (K=1024 -> 64) bf16, split-K over 4 waves ----------------
__global__ __launch_bounds__(256) void rlow_k(const ushort_t* __restrict__ r, const ushort_t* __restrict__ lrB,
                                              ushort_t* __restrict__ rlow){
    __shared__ __align__(16) float sacc[4][16][68];
    int wave = threadIdx.x>>6, lane = threadIdx.x&63;
    int m = lane&15, quad = lane>>4;
    int r0 = blockIdx.x*16;
    f32x4 acc[4];
    #pragma unroll
    for (int c=0;c<4;++c) acc[c]=(f32x4)0.f;
    const ushort_t* ab = r + (size_t)(r0+m)*D_ + wave*256 + quad*8;
    #pragma unroll
    for (int s=0;s<8;++s){
        short8 a = *(const short8*)(ab + s*32);
        #pragma unroll
        for (int c=0;c<4;++c){
            short8 b = *(const short8*)(lrB + (c*16+m)*1024 + wave*256 + s*32 + quad*8);
            acc[c] = mfma16(a, b, acc[c]);
        }
    }
    #pragma unroll
    for (int c=0;c<4;++c)
        #pragma unroll
        for (int r2=0;r2<4;++r2)
            sacc[wave][quad*4+r2][c*16+m] = acc[c][r2];
    __syncthreads();
    int row  = threadIdx.x>>4;        // 0..15
    int col4 = (threadIdx.x&15)*4;    // 0..60 step 4
    float4 v0 = *(const float4*)&sacc[0][row][col4];
    float4 v1 = *(const float4*)&sacc[1][row][col4];
    float4 v2 = *(const float4*)&sacc[2][row][col4];
    float4 v3 = *(const float4*)&sacc[3][row][col4];
    ushort4 o;
    o.x = f2bf(v0.x+v1.x+v2.x+v3.x);
    o.y = f2bf(v0.y+v1.y+v2.y+v3.y);
    o.z = f2bf(v0.z+v1.z+v2.z+v3.z);
    o.w = f2bf(v0.w+v1.w+v2.w+v3.w);
    *(ushort4*)(rlow + (size_t)(r0+row)*64 + col4) = o;
}

// ---------------- out = x + r@wloc^T + rlow@lrA^T (R7-proven form) ----------------
__global__ __launch_bounds__(256) void out_k(const float* __restrict__ x, const ushort_t* __restrict__ r,
        const ushort_t* __restrict__ rlow, const ushort_t* __restrict__ wloc, const ushort_t* __restrict__ lrA,
        float* __restrict__ out){
    __shared__ __align__(16) float st[4][16][68];
    int wave = threadIdx.x>>6, lane = threadIdx.x&63;
    int m = lane&15, quad = lane>>4;
    int orow = lane>>2, oq = lane&3;
    int n = blockIdx.y;

    short8 wl[2][4], la[4][2];
    #pragma unroll
    for (int c=0;c<4;++c)
        #pragma unroll
        for (int s=0;s<2;++s){
            wl[s][c] = *(const short8*)(wloc + n*4096 + (c*16+m)*64 + s*32 + quad*8);
            la[c][s] = *(const short8*)(lrA + (size_t)(n*64 + c*16 + m)*64 + s*32 + quad*8);
        }
    #pragma unroll
    for (int t=0;t<2;++t){
        int r0 = blockIdx.x*128 + wave*32 + t*16;
        const float* xb = x + (size_t)(r0+orow)*D_ + n*64;
        float4 xv[4];
        #pragma unroll
        for (int it=0;it<4;++it) xv[it] = *(const float4*)(xb + (it*4+oq)*4);

        const ushort_t* lb = rlow + (size_t)(r0+m)*64 + quad*8;
        short8 al0 = *(const short8*)lb;
        short8 al1 = *(const short8*)(lb + 32);
        const ushort_t* ab = r + (size_t)(r0+m)*D_ + n*64 + quad*8;
        short8 ar0 = *(const short8*)ab;
        short8 ar1 = *(const short8*)(ab + 32);
        f32x4 acc[4];
        #pragma unroll
        for (int c=0;c<4;++c){
            acc[c]=(f32x4)0.f;
            acc[c]=mfma16(al0, la[c][0], acc[c]);
            acc[c]=mfma16(al1, la[c][1], acc[c]);
            acc[c]=mfma16(ar0, wl[0][c], acc[c]);
            acc[c]=mfma16(ar1, wl[1][c], acc[c]);
        }
        #pragma unroll
        for (int c=0;c<4;++c)
            #pragma unroll
            for (int r2=0;r2<4;++r2)
                st[wave][quad*4+r2][c*16+m] = acc[c][r2];
        float* ob = out + (size_t)(r0+orow)*D_ + n*64;
        #pragma unroll
        for (int it=0;it<4;++it){
            float4 v = *(const float4*)&st[wave][orow][(it*4+oq)*4];
            v.x += xv[it].x; v.y += xv[it].y; v.z += xv[it].z; v.w += xv[it].w;
            *(float4*)(ob + (it*4+oq)*4) = v;
        }
    }
}

extern "C" void kernel_launch(void* const* d_in, const int* in_sizes, int n_in,
                              void* d_out, int out_size, void* d_ws, size_t ws_size,
                              hipStream_t stream) {
    const float* x         = (const float*)d_in[0];
    const int*   active_k  = (const int*)  d_in[1];
    const float* b_seq_w   = (const float*)d_in[2];
    const float* b_depth_w = (const float*)d_in[3];
    const float* w_post_w  = (const float*)d_in[4];
    const float* w_local_w = (const float*)d_in[5];
    const float* lr_A      = (const float*)d_in[6];
    const float* lr_B      = (const float*)d_in[7];
    const float* logA_seq  = (const float*)d_in[8];
    const float* logdt_seq = (const float*)d_in[9];
    const float* logA_dep  = (const float*)d_in[10];
    const float* logdt_dep = (const float*)d_in[11];

    float* ws      = (float*)d_ws;
    float* carry   = ws;                             // B_*NCH_*D_ = 262144
    float* aseq    = carry + (size_t)B_*NCH_*D_;
    float* apowC   = aseq + D_;
    float* gain    = apowC + D_;
    float* apowtab = gain + D_;                      // CHUNK_*D_ = 65536
    ushort_t* ub       = (ushort_t*)(apowtab + (size_t)CHUNK_*D_);
    ushort_t* e_bf     = ub;                         // R_*D_
    ushort_t* hsum_bf  = e_bf + (size_t)R_*D_;       // R_*D_ (scanned drive + hdep)
    ushort_t* hn_bf    = hsum_bf + (size_t)R_*D_;    // R_*D_ (normalized h)
    ushort_t* r_bf     = hn_bf + (size_t)R_*D_;      // R_*D_
    ushort_t* rlow_bf  = r_bf + (size_t)R_*D_;       // R_*64
    ushort_t* wseq_bf  = rlow_bf + (size_t)R_*64;    // 65536
    ushort_t* wdep_bf  = wseq_bf + 65536;
    ushort_t* wpost_bf = wdep_bf + 65536;            // 196608
    ushort_t* wloc_bf  = wpost_bf + 196608;
    ushort_t* lrA_bf   = wloc_bf + 65536;
    ushort_t* lrB_bf   = lrA_bf + 65536;

    prep_k<<<(524288 + D_ + 255)/256, 256, 0, stream>>>(
        b_seq_w, b_depth_w, w_post_w, w_local_w, lr_A, lr_B,
        wseq_bf, wdep_bf, wpost_bf, wloc_bf, lrA_bf, lrB_bf,
        logA_seq, logdt_seq, logA_dep, logdt_dep, active_k, aseq, apowC, gain, apowtab);

    rmsbf_k <<<R_, 256, 0, stream>>>(x, e_bf);
    bd2s_k  <<<dim3(R_/256, 16), 256, 0, stream>>>(e_bf, wseq_bf, wdep_bf, gain, aseq,
                                                   hsum_bf, carry);
    scan2_k <<<(B_*D_)/64, 64, 0, stream>>>(carry, apowC);
    scan3s_k<<<R_/8, 256, 0, stream>>>(hsum_bf, aseq, carry, apowtab, hn_bf);
    post_k  <<<dim3(R_/128, 16), 256, 0, stream>>>(hn_bf, e_bf, wpost_bf, r_bf);
    rlow_k  <<<R_/16, 256, 0, stream>>>(r_bf, lrB_bf, rlow_bf);
    out_k   <<<dim3(R_/128, 16), 256, 0, stream>>>(x, r_bf, rlow_bf, wloc_bf, lrA_bf, (float*)d_out);
}